// Round 13
// baseline (515.814 us; speedup 1.0000x reference)
//
#include <hip/hip_runtime.h>

// HypergraphConv: out = LN( (H diag(1/d_e) H^T x) / d_v @ W_node + x @ W_res )
//
// Round-13: aggregation GEMMs get 2x arithmetic intensity. The bits->bf16
// expansion cost per 128-k step (16 expand8 ~ 420 VALU cy) is independent of
// the dense-side tile, so the dense-dim wave tile grows 64->128 rows:
// 128 MFMA/step (was 64) against the same expansion -> MFMA-bound.
// acc[8][4] (128 VGPR, launch_bounds(256,2)), LDS 2x32KB (2 blocks/CU),
// same counted-vmcnt 2-barrier pipeline (vmcnt 16). Identical arithmetic.
// Everything else identical to round-12.
//
// Workspace (bytes):
//   wtpb     bf16 frag img 512x512 @ 0       (524,288)
//   Hb       u64  80x20480     @ 524,288     (13,107,200)
//   HTb      u64  320x5120     @ 13,631,488  (13,107,200)
//   inv_de   f32  5120         @ 26,738,688  (20,480)
//   inv_dv   f32  20480        @ 26,759,168  (81,920)
//   xpb      img  2560x256x16B @ 26,841,088  (10,485,760)
//   partialA bf16 16x256x5120  @ 37,326,848  (41,943,040)
//   t2p      img  640x256x16B  @ 79,269,888  (2,621,440)
//   partialB bf16 4x20480x256  @ 81,891,328  (41,943,040)  total ~124 MB

#define N_NODES 20000
#define M_EDGES 5000
#define MPAD    5120
#define NPAD    20480
#define NW      320
#define MW      80
#define DIN     256
#define DOUT    512
#define SPLITS  16
#define SPLITSB 4

typedef short bf16x8 __attribute__((ext_vector_type(8)));
typedef float f32x4 __attribute__((ext_vector_type(4)));
typedef unsigned long long u64;

#define MFMA16(A, B, C) __builtin_amdgcn_mfma_f32_16x16x32_bf16((A), (B), (C), 0, 0, 0)

__device__ __forceinline__ unsigned short f2b(float f) {
  unsigned u = __builtin_bit_cast(unsigned, f);
  return (unsigned short)((u + 0x7FFFu + ((u >> 16) & 1u)) >> 16);  // RNE
}

__device__ __forceinline__ float b2f(unsigned short b) {
  return __builtin_bit_cast(float, ((unsigned)b) << 16);
}

__device__ __forceinline__ void stage16(const void* g, void* l) {
  __builtin_amdgcn_global_load_lds(
      (const __attribute__((address_space(1))) unsigned int*)g,
      (__attribute__((address_space(3))) unsigned int*)l, 16, 0, 0);
}

// 8 bits -> 8 bf16 {0,1}
__device__ __forceinline__ bf16x8 expand8(unsigned b) {
  union { unsigned u[4]; bf16x8 v; } r;
  const unsigned t = b | (b << 15);
  r.u[0] = (t & 0x00010001u) * 0x3F80u;
  r.u[1] = ((t >> 2) & 0x00010001u) * 0x3F80u;
  r.u[2] = ((t >> 4) & 0x00010001u) * 0x3F80u;
  r.u[3] = ((t >> 6) & 0x00010001u) * 0x3F80u;
  return r.v;
}

// ---------------------------------------------------------------- prep: wtpb frag image
__global__ __launch_bounds__(256) void prep_kernel(const float* __restrict__ Wn,
                                                   const float* __restrict__ Wr,
                                                   unsigned short* __restrict__ wtpb) {
  const int q = blockIdx.x * 256 + threadIdx.x;  // < 262144
  const int j = q >> 9, k = q & 511;
  const float v = (k < 256) ? Wn[(size_t)k * 512 + j] : Wr[(size_t)(k - 256) * 512 + j];
  wtpb[(((size_t)(k >> 3) * 512 + j) << 3) + (k & 7)] = f2b(v);
}

// ---------------------------------------------------------------- xt
__global__ __launch_bounds__(256) void xt_kernel(const float* __restrict__ x,
                                                 unsigned short* __restrict__ xpb) {
  const int j = threadIdx.x;
  const int n8 = blockIdx.x;
  union { unsigned u[4]; bf16x8 v; } o;
#pragma unroll
  for (int p = 0; p < 4; ++p) {
    const int n = n8 * 8 + 2 * p;
    const float v0 = (n < N_NODES) ? x[(size_t)n * DIN + j] : 0.f;
    const float v1 = (n + 1 < N_NODES) ? x[(size_t)(n + 1) * DIN + j] : 0.f;
    o.u[p] = (unsigned)f2b(v0) | ((unsigned)f2b(v1) << 16);
  }
  *(bf16x8*)(xpb + ((size_t)n8 * 256 + j) * 8) = o.v;
}

// ---------------------------------------------------------------- pack v4 (r10-proven)
__global__ __launch_bounds__(256) void pack_kernel(const float* __restrict__ H,
                                                   u64* __restrict__ HTb) {
  const int t = threadIdx.x;
  const int g = blockIdx.x;        // 0..319
  const int h = blockIdx.y;        // 0..4
  const int n0 = g * 64;
  const int mc = h * 1024 + 4 * t;
  u64 h0 = 0, h1 = 0, h2 = 0, h3 = 0;
  if (mc + 3 < M_EDGES) {
    const float* col = H + mc;
#pragma unroll 4
    for (int r = 0; r < 64; ++r) {
      const int n = n0 + r;
      if (n < N_NODES) {
        const float4 v = *(const float4*)(col + (size_t)n * M_EDGES);
        h0 |= (u64)(v.x != 0.f) << r;
        h1 |= (u64)(v.y != 0.f) << r;
        h2 |= (u64)(v.z != 0.f) << r;
        h3 |= (u64)(v.w != 0.f) << r;
      }
    }
  } else if (mc < M_EDGES) {
    for (int r = 0; r < 64; ++r) {
      const int n = n0 + r;
      if (n < N_NODES) {
        const float* row = H + (size_t)n * M_EDGES;
        if (mc + 0 < M_EDGES) h0 |= (u64)(row[mc + 0] != 0.f) << r;
        if (mc + 1 < M_EDGES) h1 |= (u64)(row[mc + 1] != 0.f) << r;
        if (mc + 2 < M_EDGES) h2 |= (u64)(row[mc + 2] != 0.f) << r;
        if (mc + 3 < M_EDGES) h3 |= (u64)(row[mc + 3] != 0.f) << r;
      }
    }
  }
  u64* hp = HTb + (size_t)g * MPAD + mc;
  hp[0] = h0; hp[1] = h1; hp[2] = h2; hp[3] = h3;
}

// ---------------------------------------------------------------- bt: bit-transpose HTb -> Hb
__global__ __launch_bounds__(256) void bt_kernel(const u64* __restrict__ HTb,
                                                 u64* __restrict__ Hb) {
  const int t = threadIdx.x;
  const int w = t >> 6, l = t & 63;
  const int id = blockIdx.x * 4 + w;
  const int nw = id % NW;
  const int mw = id / NW;
  const u64 word = HTb[(size_t)nw * MPAD + mw * 64 + l];
  u64 out = 0;
  for (int r = 0; r < 64; ++r) {
    const u64 mask = __ballot(((word >> r) & 1ull) != 0);
    if (l == r) out = mask;
  }
  Hb[(size_t)mw * NPAD + nw * 64 + l] = out;
}

// ---------------------------------------------------------------- deg
__global__ __launch_bounds__(256) void deg_kernel(const u64* __restrict__ Hb,
                                                  const u64* __restrict__ HTb,
                                                  float* __restrict__ inv_de,
                                                  float* __restrict__ inv_dv) {
  const int g = blockIdx.x * 256 + threadIdx.x;
  if (g < MPAD) {
    int c = 0;
    for (int nw = 0; nw < NW; ++nw) c += __popcll(HTb[(size_t)nw * MPAD + g]);
    inv_de[g] = 1.f / fmaxf((float)c, 1.f);
  } else if (g < MPAD + NPAD) {
    const int n = g - MPAD;
    int c = 0;
#pragma unroll
    for (int mw = 0; mw < MW; ++mw) c += __popcll(Hb[(size_t)mw * NPAD + n]);
    inv_dv[n] = 1.f / fmaxf((float)c, 1.f);
  }
}

// ---------------------------------------------------------------- gemmA: partialA[s] = bf16(x^T @ H)
// 4 waves; block tile 128j x 256m (wave-private 64m); split-K 16, 10 steps x 128n.
// Wave tile 128j x 64m: acc[8][4]; 128 MFMA vs 16 expand8 per step.
__global__ __launch_bounds__(256, 2) void gemmA_kernel(const unsigned short* __restrict__ xpb,
                                                       const u64* __restrict__ HTb,
                                                       unsigned short* __restrict__ partial) {
  __shared__ char lds[2][32768];   // [16 k8][128 j] x16B per buffer
  const int t = threadIdx.x;
  const int w = t >> 6, l = t & 63;
  const int lr = l & 15, lg = l >> 4;
  const int shl8 = lg * 8;
  const int wgid = blockIdx.x;     // 640
  const int mchunk = wgid >> 5;    // 0..19
  const int sj = wgid & 31;
  const int s = sj >> 1, jb = sj & 1;
  const int m0 = mchunk * 256 + w * 64;
  const int j0 = jb * 128;

  f32x4 acc[8][4] = {};
  const u64* bbase = HTb + (size_t)(s * 20) * MPAD + m0 + lr;
  const char* xb = (const char*)xpb;
  const int n8b = s * 160;

  u64 b00, b01, b02, b03, b04, b05, b06, b07;
  u64 b10, b11, b12, b13, b14, b15, b16, b17;

#define GA_LOADB(S, st_) do {                                                  \
    const u64* bp_ = bbase + (size_t)(st_) * 2 * MPAD;                         \
    b##S##0 = bp_[0]; b##S##1 = bp_[16]; b##S##2 = bp_[32]; b##S##3 = bp_[48]; \
    const u64* bq_ = bp_ + MPAD;                                               \
    b##S##4 = bq_[0]; b##S##5 = bq_[16]; b##S##6 = bq_[32]; b##S##7 = bq_[48]; \
  } while (0)

#define GA_STAGE(buf, st_) do {                                                \
    const int bn_ = n8b + (st_) * 16 + (t >> 7);                               \
    const int jj_ = j0 + (t & 127);                                            \
    stage16(xb + ((size_t)(bn_ +  0) * 256 + jj_) * 16, &lds[buf][0 * 4096 + t * 16]); \
    stage16(xb + ((size_t)(bn_ +  2) * 256 + jj_) * 16, &lds[buf][1 * 4096 + t * 16]); \
    stage16(xb + ((size_t)(bn_ +  4) * 256 + jj_) * 16, &lds[buf][2 * 4096 + t * 16]); \
    stage16(xb + ((size_t)(bn_ +  6) * 256 + jj_) * 16, &lds[buf][3 * 4096 + t * 16]); \
    stage16(xb + ((size_t)(bn_ +  8) * 256 + jj_) * 16, &lds[buf][4 * 4096 + t * 16]); \
    stage16(xb + ((size_t)(bn_ + 10) * 256 + jj_) * 16, &lds[buf][5 * 4096 + t * 16]); \
    stage16(xb + ((size_t)(bn_ + 12) * 256 + jj_) * 16, &lds[buf][6 * 4096 + t * 16]); \
    stage16(xb + ((size_t)(bn_ + 14) * 256 + jj_) * 16, &lds[buf][7 * 4096 + t * 16]); \
  } while (0)

#define GA_KS(buf, ks, sh, W0, W1, W2, W3) do {                                \
    const char* Lb_ = &lds[buf][((ks) * 4 + lg) * 2048 + lr * 16];             \
    const bf16x8 A0_ = *(const bf16x8*)(Lb_ + 0);                              \
    const bf16x8 A1_ = *(const bf16x8*)(Lb_ + 256);                            \
    const bf16x8 A2_ = *(const bf16x8*)(Lb_ + 512);                            \
    const bf16x8 A3_ = *(const bf16x8*)(Lb_ + 768);                            \
    const bf16x8 A4_ = *(const bf16x8*)(Lb_ + 1024);                           \
    const bf16x8 A5_ = *(const bf16x8*)(Lb_ + 1280);                           \
    const bf16x8 A6_ = *(const bf16x8*)(Lb_ + 1536);                           \
    const bf16x8 A7_ = *(const bf16x8*)(Lb_ + 1792);                           \
    bf16x8 e_;                                                                 \
    e_ = expand8(((unsigned)((W0) >> (sh)) >> shl8) & 255u);                   \
    acc[0][0] = MFMA16(A0_, e_, acc[0][0]);                                    \
    acc[1][0] = MFMA16(A1_, e_, acc[1][0]);                                    \
    acc[2][0] = MFMA16(A2_, e_, acc[2][0]);                                    \
    acc[3][0] = MFMA16(A3_, e_, acc[3][0]);                                    \
    acc[4][0] = MFMA16(A4_, e_, acc[4][0]);                                    \
    acc[5][0] = MFMA16(A5_, e_, acc[5][0]);                                    \
    acc[6][0] = MFMA16(A6_, e_, acc[6][0]);                                    \
    acc[7][0] = MFMA16(A7_, e_, acc[7][0]);                                    \
    e_ = expand8(((unsigned)((W1) >> (sh)) >> shl8) & 255u);                   \
    acc[0][1] = MFMA16(A0_, e_, acc[0][1]);                                    \
    acc[1][1] = MFMA16(A1_, e_, acc[1][1]);                                    \
    acc[2][1] = MFMA16(A2_, e_, acc[2][1]);                                    \
    acc[3][1] = MFMA16(A3_, e_, acc[3][1]);                                    \
    acc[4][1] = MFMA16(A4_, e_, acc[4][1]);                                    \
    acc[5][1] = MFMA16(A5_, e_, acc[5][1]);                                    \
    acc[6][1] = MFMA16(A6_, e_, acc[6][1]);                                    \
    acc[7][1] = MFMA16(A7_, e_, acc[7][1]);                                    \
    e_ = expand8(((unsigned)((W2) >> (sh)) >> shl8) & 255u);                   \
    acc[0][2] = MFMA16(A0_, e_, acc[0][2]);                                    \
    acc[1][2] = MFMA16(A1_, e_, acc[1][2]);                                    \
    acc[2][2] = MFMA16(A2_, e_, acc[2][2]);                                    \
    acc[3][2] = MFMA16(A3_, e_, acc[3][2]);                                    \
    acc[4][2] = MFMA16(A4_, e_, acc[4][2]);                                    \
    acc[5][2] = MFMA16(A5_, e_, acc[5][2]);                                    \
    acc[6][2] = MFMA16(A6_, e_, acc[6][2]);                                    \
    acc[7][2] = MFMA16(A7_, e_, acc[7][2]);                                    \
    e_ = expand8(((unsigned)((W3) >> (sh)) >> shl8) & 255u);                   \
    acc[0][3] = MFMA16(A0_, e_, acc[0][3]);                                    \
    acc[1][3] = MFMA16(A1_, e_, acc[1][3]);                                    \
    acc[2][3] = MFMA16(A2_, e_, acc[2][3]);                                    \
    acc[3][3] = MFMA16(A3_, e_, acc[3][3]);                                    \
    acc[4][3] = MFMA16(A4_, e_, acc[4][3]);                                    \
    acc[5][3] = MFMA16(A5_, e_, acc[5][3]);                                    \
    acc[6][3] = MFMA16(A6_, e_, acc[6][3]);                                    \
    acc[7][3] = MFMA16(A7_, e_, acc[7][3]);                                    \
  } while (0)

  GA_LOADB(0, 0);
  GA_STAGE(0, 0);
  for (int st = 0; st < 10; st += 2) {
    const int n1 = (st + 1 < 10) ? st + 1 : 9;
    GA_LOADB(1, n1); GA_STAGE(1, n1);
    asm volatile("s_waitcnt vmcnt(16)" ::: "memory");
    __builtin_amdgcn_s_barrier();
    GA_KS(0, 0, 0,  b00, b01, b02, b03);
    GA_KS(0, 1, 32, b00, b01, b02, b03);
    GA_KS(0, 2, 0,  b04, b05, b06, b07);
    GA_KS(0, 3, 32, b04, b05, b06, b07);
    __builtin_amdgcn_s_barrier();
    const int n2 = (st + 2 < 10) ? st + 2 : 9;
    GA_LOADB(0, n2); GA_STAGE(0, n2);
    asm volatile("s_waitcnt vmcnt(16)" ::: "memory");
    __builtin_amdgcn_s_barrier();
    GA_KS(1, 0, 0,  b10, b11, b12, b13);
    GA_KS(1, 1, 32, b10, b11, b12, b13);
    GA_KS(1, 2, 0,  b14, b15, b16, b17);
    GA_KS(1, 3, 32, b14, b15, b16, b17);
    __builtin_amdgcn_s_barrier();
  }
#undef GA_LOADB
#undef GA_STAGE
#undef GA_KS

  unsigned short* pp = partial + (size_t)s * (DIN * MPAD);
#pragma unroll
  for (int fr = 0; fr < 8; ++fr)
#pragma unroll
    for (int r = 0; r < 4; ++r) {
      const int j = j0 + fr * 16 + lg * 4 + r;
#pragma unroll
      for (int mg = 0; mg < 4; ++mg)
        pp[(size_t)j * MPAD + m0 + mg * 16 + lr] = f2b(acc[fr][mg][r]);
    }
}

// ---------------------------------------------------------------- reduceA (bf16 partials)
__global__ __launch_bounds__(256) void reduceA_kernel(const unsigned short* __restrict__ partial,
                                                      const float* __restrict__ inv_de,
                                                      unsigned short* __restrict__ t2p) {
  const int t = threadIdx.x;
  const int m = blockIdx.x * 256 + t;
  const int jc = blockIdx.y * 16;
  const float e = inv_de[m];
  unsigned short* ob = t2p + ((size_t)(m >> 3) * 256) * 8 + (m & 7);
  for (int jj = 0; jj < 16; ++jj) {
    const int j = jc + jj;
    const unsigned short* p = partial + (size_t)j * MPAD + m;
    float s = 0.f;
#pragma unroll
    for (int sp = 0; sp < SPLITS; ++sp) s += b2f(p[(size_t)sp * (DIN * MPAD)]);
    ob[(size_t)j * 8] = f2b(s * e);
  }
}

// ---------------------------------------------------------------- gemmB: partialB[s] = bf16(H @ T2)
// 4 waves; block tile 256n x 128j (wave-private 64n); split-K 4, 10 steps x 128m.
// Wave tile 64n x 128j: acc[4][8]; 128 MFMA vs 16 expand8 per step.
__global__ __launch_bounds__(256, 2) void gemmB_kernel(const unsigned short* __restrict__ t2p,
                                                       const u64* __restrict__ Hb,
                                                       unsigned short* __restrict__ partialB) {
  __shared__ char lds[2][32768];   // [16 k8][128 j] x16B per buffer
  const int t = threadIdx.x;
  const int w = t >> 6, l = t & 63;
  const int lr = l & 15, lg = l >> 4;
  const int shl8 = lg * 8;
  const int wgid = blockIdx.x;     // 640
  const int nchunk = wgid >> 3;    // 0..79
  const int sj = wgid & 7;
  const int s = sj >> 1, jb = sj & 1;
  const int n0 = nchunk * 256 + w * 64;
  const int j0 = jb * 128;

  f32x4 acc[4][8] = {};
  const u64* abase = Hb + (size_t)(s * 20) * NPAD + n0 + lr;
  const char* tb = (const char*)t2p;
  const int m8b = s * 160;

  u64 a00, a01, a02, a03, a04, a05, a06, a07;
  u64 a10, a11, a12, a13, a14, a15, a16, a17;

#define GB_LOADA(S, st_) do {                                                  \
    const u64* ap_ = abase + (size_t)(st_) * 2 * NPAD;                         \
    a##S##0 = ap_[0]; a##S##1 = ap_[16]; a##S##2 = ap_[32]; a##S##3 = ap_[48]; \
    const u64* aq_ = ap_ + NPAD;                                               \
    a##S##4 = aq_[0]; a##S##5 = aq_[16]; a##S##6 = aq_[32]; a##S##7 = aq_[48]; \
  } while (0)

#define GB_STAGE(buf, st_) do {                                                \
    const int bm_ = m8b + (st_) * 16 + (t >> 7);                               \
    const int jj_ = j0 + (t & 127);                                            \
    stage16(tb + ((size_t)(bm_ +  0) * 256 + jj_) * 16, &lds[buf][0 * 4096 + t * 16]); \
    stage16(tb + ((size_t)(bm_ +  2) * 256 + jj_) * 16, &lds[buf][1 * 4096 + t * 16]); \
    stage16(tb + ((size_t)(bm_ +  4) * 256 + jj_) * 16, &lds[buf][2 * 4096 + t * 16]); \
    stage16(tb + ((size_t)(bm_ +  6) * 256 + jj_) * 16, &lds[buf][3 * 4096 + t * 16]); \
    stage16(tb + ((size_t)(bm_ +  8) * 256 + jj_) * 16, &lds[buf][4 * 4096 + t * 16]); \
    stage16(tb + ((size_t)(bm_ + 10) * 256 + jj_) * 16, &lds[buf][5 * 4096 + t * 16]); \
    stage16(tb + ((size_t)(bm_ + 12) * 256 + jj_) * 16, &lds[buf][6 * 4096 + t * 16]); \
    stage16(tb + ((size_t)(bm_ + 14) * 256 + jj_) * 16, &lds[buf][7 * 4096 + t * 16]); \
  } while (0)

#define GB_KS(buf, ks, sh, W0, W1, W2, W3) do {                                \
    const char* Lb_ = &lds[buf][((ks) * 4 + lg) * 2048 + lr * 16];             \
    const bf16x8 B0_ = *(const bf16x8*)(Lb_ + 0);                              \
    const bf16x8 B1_ = *(const bf16x8*)(Lb_ + 256);                            \
    const bf16x8 B2_ = *(const bf16x8*)(Lb_ + 512);                            \
    const bf16x8 B3_ = *(const bf16x8*)(Lb_ + 768);                            \
    const bf16x8 B4_ = *(const bf16x8*)(Lb_ + 1024);                           \
    const bf16x8 B5_ = *(const bf16x8*)(Lb_ + 1280);                           \
    const bf16x8 B6_ = *(const bf16x8*)(Lb_ + 1536);                           \
    const bf16x8 B7_ = *(const bf16x8*)(Lb_ + 1792);                           \
    bf16x8 e_;                                                                 \
    e_ = expand8(((unsigned)((W0) >> (sh)) >> shl8) & 255u);                   \
    acc[0][0] = MFMA16(e_, B0_, acc[0][0]);                                    \
    acc[0][1] = MFMA16(e_, B1_, acc[0][1]);                                    \
    acc[0][2] = MFMA16(e_, B2_, acc[0][2]);                                    \
    acc[0][3] = MFMA16(e_, B3_, acc[0][3]);                                    \
    acc[0][4] = MFMA16(e_, B4_, acc[0][4]);                                    \
    acc[0][5] = MFMA16(e_, B5_, acc[0][5]);                                    \
    acc[0][6] = MFMA16(e_, B6_, acc[0][6]);                                    \
    acc[0][7] = MFMA16(e_, B7_, acc[0][7]);                                    \
    e_ = expand8(((unsigned)((W1) >> (sh)) >> shl8) & 255u);                   \
    acc[1][0] = MFMA16(e_, B0_, acc[1][0]);                                    \
    acc[1][1] = MFMA16(e_, B1_, acc[1][1]);                                    \
    acc[1][2] = MFMA16(e_, B2_, acc[1][2]);                                    \
    acc[1][3] = MFMA16(e_, B3_, acc[1][3]);                                    \
    acc[1][4] = MFMA16(e_, B4_, acc[1][4]);                                    \
    acc[1][5] = MFMA16(e_, B5_, acc[1][5]);                                    \
    acc[1][6] = MFMA16(e_, B6_, acc[1][6]);                                    \
    acc[1][7] = MFMA16(e_, B7_, acc[1][7]);                                    \
    e_ = expand8(((unsigned)((W2) >> (sh)) >> shl8) & 255u);                   \
    acc[2][0] = MFMA16(e_, B0_, acc[2][0]);                                    \
    acc[2][1] = MFMA16(e_, B1_, acc[2][1]);                                    \
    acc[2][2] = MFMA16(e_, B2_, acc[2][2]);                                    \
    acc[2][3] = MFMA16(e_, B3_, acc[2][3]);                                    \
    acc[2][4] = MFMA16(e_, B4_, acc[2][4]);                                    \
    acc[2][5] = MFMA16(e_, B5_, acc[2][5]);                                    \
    acc[2][6] = MFMA16(e_, B6_, acc[2][6]);                                    \
    acc[2][7] = MFMA16(e_, B7_, acc[2][7]);                                    \
    e_ = expand8(((unsigned)((W3) >> (sh)) >> shl8) & 255u);                   \
    acc[3][0] = MFMA16(e_, B0_, acc[3][0]);                                    \
    acc[3][1] = MFMA16(e_, B1_, acc[3][1]);                                    \
    acc[3][2] = MFMA16(e_, B2_, acc[3][2]);                                    \
    acc[3][3] = MFMA16(e_, B3_, acc[3][3]);                                    \
    acc[3][4] = MFMA16(e_, B4_, acc[3][4]);                                    \
    acc[3][5] = MFMA16(e_, B5_, acc[3][5]);                                    \
    acc[3][6] = MFMA16(e_, B6_, acc[3][6]);                                    \
    acc[3][7] = MFMA16(e_, B7_, acc[3][7]);                                    \
  } while (0)

  GB_LOADA(0, 0);
  GB_STAGE(0, 0);
  for (int st = 0; st < 10; st += 2) {
    const int n1 = (st + 1 < 10) ? st + 1 : 9;
    GB_LOADA(1, n1); GB_STAGE(1, n1);
    asm volatile("s_waitcnt vmcnt(16)" ::: "memory");
    __builtin_amdgcn_s_barrier();
    GB_KS(0, 0, 0,  a00, a01, a02, a03);
    GB_KS(0, 1, 32, a00, a01, a02, a03);
    GB_KS(0, 2, 0,  a04, a05, a06, a07);
    GB_KS(0, 3, 32, a04, a05, a06, a07);
    __builtin_amdgcn_s_barrier();
    const int n2 = (st + 2 < 10) ? st + 2 : 9;
    GB_LOADA(0, n2); GB_STAGE(0, n2);
    asm volatile("s_waitcnt vmcnt(16)" ::: "memory");
    __builtin_amdgcn_s_barrier();
    GB_KS(1, 0, 0,  a10, a11, a12, a13);
    GB_KS(1, 1, 32, a10, a11, a12, a13);
    GB_KS(1, 2, 0,  a14, a15, a16, a17);
    GB_KS(1, 3, 32, a14, a15, a16, a17);
    __builtin_amdgcn_s_barrier();
  }
#undef GB_LOADA
#undef GB_STAGE
#undef GB_KS

  unsigned short* pp = partialB + (size_t)s * ((size_t)NPAD * DIN);
#pragma unroll
  for (int fn = 0; fn < 4; ++fn) {
#pragma unroll
    for (int r = 0; r < 4; ++r) {
      const int n = n0 + fn * 16 + lg * 4 + r;
#pragma unroll
      for (int fj = 0; fj < 8; ++fj)
        pp[(size_t)n * DIN + j0 + fj * 16 + lr] = f2b(acc[fn][fj][r]);
    }
  }
}

// ---------------------------------------------------------------- gemmC2 v2 (r12-proven): fused reduceB + [T3|x]@WT + LN
__global__ __launch_bounds__(512) void gemmC2_kernel(const unsigned short* __restrict__ partialB,
                                                     const float* __restrict__ inv_dv,
                                                     const float* __restrict__ x,
                                                     const unsigned short* __restrict__ wtpb,
                                                     const float* __restrict__ gamma,
                                                     const float* __restrict__ beta,
                                                     float* __restrict__ out) {
  __shared__ char ldsA[65536];        // A tile: 64 rows x 512 k bf16 (1024B rows, xor-swz)
  __shared__ float lnred[2][64][8];
  const int t = threadIdx.x;
  const int w = t >> 6, l = t & 63;
  const int lr = l & 15, lg = l >> 4;
  const int n0 = blockIdx.x * 64;

  // Phase 1: T3 tile = bf16((sum_sp partialB) * inv_dv) -> ldsA k<256
  {
    const int k8 = t & 31;
    const int rb = t >> 5;
#pragma unroll
    for (int pass = 0; pass < 4; ++pass) {
      const int r = pass * 16 + rb;
      const size_t base = (size_t)(n0 + r) * 256 + k8 * 8;
      float sum[8] = {0.f, 0.f, 0.f, 0.f, 0.f, 0.f, 0.f, 0.f};
#pragma unroll
      for (int sp = 0; sp < SPLITSB; ++sp) {
        const bf16x8 v = *(const bf16x8*)(partialB + (size_t)sp * ((size_t)NPAD * DIN) + base);
#pragma unroll
        for (int i = 0; i < 8; ++i) sum[i] += b2f((unsigned short)v[i]);
      }
      const float dv = inv_dv[n0 + r];
      union { unsigned u[4]; bf16x8 v; } o;
#pragma unroll
      for (int p = 0; p < 4; ++p)
        o.u[p] = (unsigned)f2b(sum[2 * p] * dv) | ((unsigned)f2b(sum[2 * p + 1] * dv) << 16);
      *(bf16x8*)(ldsA + r * 1024 + ((k8 * 16) ^ ((r & 7) << 4))) = o.v;
    }
  }
  // Phase 2: x tile -> ldsA k in [256,512)
  {
    const int c4 = t & 63;
    const int rb = t >> 6;
#pragma unroll
    for (int pass = 0; pass < 8; ++pass) {
      const int r = pass * 8 + rb;
      float4 v = make_float4(0.f, 0.f, 0.f, 0.f);
      if (n0 + r < N_NODES) v = *(const float4*)(x + (size_t)(n0 + r) * DIN + c4 * 4);
      const unsigned u0 = (unsigned)f2b(v.x) | ((unsigned)f2b(v.y) << 16);
      const unsigned u1 = (unsigned)f2b(v.z) | ((unsigned)f2b(v.w) << 16);
      const int byte0 = 512 + c4 * 8;
      const int off = ((byte0 & ~15) ^ ((r & 7) << 4)) + (byte0 & 8);
      *(uint2*)(ldsA + r * 1024 + off) = make_uint2(u0, u1);
    }
  }
  __syncthreads();

  f32x4 acc[4][4] = {};
  const int wcol = w * 64;
#pragma unroll 2
  for (int kt = 0; kt < 16; ++kt) {
    bf16x8 bf[4];
#pragma unroll
    for (int jg = 0; jg < 4; ++jg) {
      const int col = wcol + jg * 16 + lr;
      bf[jg] = *(const bf16x8*)(wtpb + (((size_t)(kt * 4 + lg) * 512 + col) << 3));
    }
    const int kbA = kt * 64 + lg * 16;
#pragma unroll
    for (int fr = 0; fr < 4; ++fr) {
      const int row = fr * 16 + lr;
      const bf16x8 af = *(const bf16x8*)(ldsA + row * 1024 + (kbA ^ ((row & 7) << 4)));
#pragma unroll
      for (int jg = 0; jg < 4; ++jg)
        acc[fr][jg] = MFMA16(af, bf[jg], acc[fr][jg]);
    }
  }

#pragma unroll
  for (int fr = 0; fr < 4; ++fr)
#pragma unroll
    for (int r = 0; r < 4; ++r) {
      float s = 0.f, s2 = 0.f;
#pragma unroll
      for (int jg = 0; jg < 4; ++jg) {
        const float v = acc[fr][jg][r];
        s += v; s2 += v * v;
      }
#pragma unroll
      for (int m = 1; m < 16; m <<= 1) {
        s += __shfl_xor(s, m, 64);
        s2 += __shfl_xor(s2, m, 64);
      }
      if (lr == 0) {
        const int row = fr * 16 + lg * 4 + r;
        lnred[0][row][w] = s;
        lnred[1][row][w] = s2;
      }
    }
  __syncthreads();

#pragma unroll
  for (int fr = 0; fr < 4; ++fr) {
#pragma unroll
    for (int r = 0; r < 4; ++r) {
      const int row = fr * 16 + lg * 4 + r;
      float S = 0.f, S2 = 0.f;
#pragma unroll
      for (int ww = 0; ww < 8; ++ww) { S += lnred[0][row][ww]; S2 += lnred[1][row][ww]; }
      const float mu = S * (1.f / 512.f);
      const float rs = rsqrtf(S2 * (1.f / 512.f) - mu * mu + 1e-5f);
      const int gn = n0 + row;
      if (gn < N_NODES) {
#pragma unroll
        for (int jg = 0; jg < 4; ++jg) {
          const int col = wcol + jg * 16 + lr;
          out[(size_t)gn * DOUT + col] = (acc[fr][jg][r] - mu) * rs * gamma[col] + beta[col];
        }
      }
    }
  }
}

// ----------------------------------------------------------------
extern "C" void kernel_launch(void* const* d_in, const int* in_sizes, int n_in,
                              void* d_out, int out_size, void* d_ws, size_t ws_size,
                              hipStream_t stream) {
  (void)in_sizes; (void)n_in; (void)out_size; (void)ws_size;
  const float* x = (const float*)d_in[0];
  const float* H = (const float*)d_in[1];
  const float* Wn = (const float*)d_in[2];
  const float* Wr = (const float*)d_in[3];
  const float* gamma = (const float*)d_in[4];
  const float* beta = (const float*)d_in[5];
  float* out = (float*)d_out;
  char* ws = (char*)d_ws;

  unsigned short* wtpb     = (unsigned short*)(ws + 0);
  u64* Hb                  = (u64*)(ws + 524288);
  u64* HTb                 = (u64*)(ws + 13631488);
  float* inv_de            = (float*)(ws + 26738688);
  float* inv_dv            = (float*)(ws + 26759168);
  unsigned short* xpb      = (unsigned short*)(ws + 26841088);
  unsigned short* partialA = (unsigned short*)(ws + 37326848);
  unsigned short* t2p      = (unsigned short*)(ws + 79269888);
  unsigned short* partialB = (unsigned short*)(ws + 81891328);

  prep_kernel<<<dim3(1024), dim3(256), 0, stream>>>(Wn, Wr, wtpb);
  xt_kernel<<<dim3(2560), dim3(256), 0, stream>>>(x, xpb);
  pack_kernel<<<dim3(320, 5), dim3(256), 0, stream>>>(H, HTb);
  bt_kernel<<<dim3(6400), dim3(256), 0, stream>>>(HTb, Hb);
  deg_kernel<<<dim3(100), dim3(256), 0, stream>>>(Hb, HTb, inv_de, inv_dv);
  gemmA_kernel<<<dim3(640), dim3(256), 0, stream>>>(xpb, HTb, partialA);
  reduceA_kernel<<<dim3(20, 16), dim3(256), 0, stream>>>(partialA, inv_de, t2p);
  gemmB_kernel<<<dim3(640), dim3(256), 0, stream>>>(t2p, Hb, partialB);
  gemmC2_kernel<<<dim3(313), dim3(512), 0, stream>>>(partialB, inv_dv, x, wtpb,
                                                     gamma, beta, out);
}

// Round 14
// 324.311 us; speedup vs baseline: 1.5905x; 1.5905x over previous
//
#include <hip/hip_runtime.h>

// HypergraphConv: out = LN( (H diag(1/d_e) H^T x) / d_v @ W_node + x @ W_res )
//
// Round-14: REVERT to round-12 (319us proven; round-13's 128-row wave tiles
// regressed to 516us via VGPR pressure + LDS-capacity tail) + ONE tweak:
// pack v5 splits row-groups 64->32 (grid 640x5 = 3200 blocks, 12.5/CU vs
// 6.25), accumulating 4 u32 half-words and storing u64 halves directly
// (disjoint u32 stores, no RMW). Same stream pattern, 2x TLP.
//
// Workspace (bytes):
//   wtpb     bf16 frag img 512x512 @ 0       (524,288)
//   Hb       u64  80x20480     @ 524,288     (13,107,200)
//   HTb      u64  320x5120     @ 13,631,488  (13,107,200)
//   inv_de   f32  5120         @ 26,738,688  (20,480)
//   inv_dv   f32  20480        @ 26,759,168  (81,920)
//   xpb      img  2560x256x16B @ 26,841,088  (10,485,760)
//   partialA bf16 16x256x5120  @ 37,326,848  (41,943,040)
//   t2p      img  640x256x16B  @ 79,269,888  (2,621,440)
//   partialB bf16 4x20480x256  @ 81,891,328  (41,943,040)  total ~124 MB

#define N_NODES 20000
#define M_EDGES 5000
#define MPAD    5120
#define NPAD    20480
#define NW      320
#define MW      80
#define DIN     256
#define DOUT    512
#define SPLITS  16
#define SPLITSB 4

typedef short bf16x8 __attribute__((ext_vector_type(8)));
typedef float f32x4 __attribute__((ext_vector_type(4)));
typedef unsigned long long u64;

#define MFMA16(A, B, C) __builtin_amdgcn_mfma_f32_16x16x32_bf16((A), (B), (C), 0, 0, 0)

__device__ __forceinline__ unsigned short f2b(float f) {
  unsigned u = __builtin_bit_cast(unsigned, f);
  return (unsigned short)((u + 0x7FFFu + ((u >> 16) & 1u)) >> 16);  // RNE
}

__device__ __forceinline__ float b2f(unsigned short b) {
  return __builtin_bit_cast(float, ((unsigned)b) << 16);
}

__device__ __forceinline__ void stage16(const void* g, void* l) {
  __builtin_amdgcn_global_load_lds(
      (const __attribute__((address_space(1))) unsigned int*)g,
      (__attribute__((address_space(3))) unsigned int*)l, 16, 0, 0);
}

// 8 bits -> 8 bf16 {0,1}
__device__ __forceinline__ bf16x8 expand8(unsigned b) {
  union { unsigned u[4]; bf16x8 v; } r;
  const unsigned t = b | (b << 15);
  r.u[0] = (t & 0x00010001u) * 0x3F80u;
  r.u[1] = ((t >> 2) & 0x00010001u) * 0x3F80u;
  r.u[2] = ((t >> 4) & 0x00010001u) * 0x3F80u;
  r.u[3] = ((t >> 6) & 0x00010001u) * 0x3F80u;
  return r.v;
}

// ---------------------------------------------------------------- prep: wtpb frag image
__global__ __launch_bounds__(256) void prep_kernel(const float* __restrict__ Wn,
                                                   const float* __restrict__ Wr,
                                                   unsigned short* __restrict__ wtpb) {
  const int q = blockIdx.x * 256 + threadIdx.x;  // < 262144
  const int j = q >> 9, k = q & 511;
  const float v = (k < 256) ? Wn[(size_t)k * 512 + j] : Wr[(size_t)(k - 256) * 512 + j];
  wtpb[(((size_t)(k >> 3) * 512 + j) << 3) + (k & 7)] = f2b(v);
}

// ---------------------------------------------------------------- xt
__global__ __launch_bounds__(256) void xt_kernel(const float* __restrict__ x,
                                                 unsigned short* __restrict__ xpb) {
  const int j = threadIdx.x;
  const int n8 = blockIdx.x;
  union { unsigned u[4]; bf16x8 v; } o;
#pragma unroll
  for (int p = 0; p < 4; ++p) {
    const int n = n8 * 8 + 2 * p;
    const float v0 = (n < N_NODES) ? x[(size_t)n * DIN + j] : 0.f;
    const float v1 = (n + 1 < N_NODES) ? x[(size_t)(n + 1) * DIN + j] : 0.f;
    o.u[p] = (unsigned)f2b(v0) | ((unsigned)f2b(v1) << 16);
  }
  *(bf16x8*)(xpb + ((size_t)n8 * 256 + j) * 8) = o.v;
}

// ---------------------------------------------------------------- pack v5: 32-row groups, u32 half-word stores
// grid (640, 5): block = 32 rows x 1024 cols. Thread owns 4 fixed cols
// (one float4 per row); 4 u32 accumulated; stores the u64's low/high half.
__global__ __launch_bounds__(256) void pack_kernel(const float* __restrict__ H,
                                                   unsigned* __restrict__ HTb32) {
  const int t = threadIdx.x;
  const int gg = blockIdx.x;       // 0..639 (32-row group)
  const int h = blockIdx.y;        // 0..4   (1024-col group)
  const int g = gg >> 1, half = gg & 1;
  const int n0 = gg * 32;
  const int mc = h * 1024 + 4 * t; // this thread's 4 columns
  unsigned h0 = 0, h1 = 0, h2 = 0, h3 = 0;
  if (mc + 3 < M_EDGES) {
    const float* col = H + mc;
#pragma unroll 4
    for (int r = 0; r < 32; ++r) {
      const int n = n0 + r;
      if (n < N_NODES) {
        const float4 v = *(const float4*)(col + (size_t)n * M_EDGES);
        h0 |= (unsigned)(v.x != 0.f) << r;
        h1 |= (unsigned)(v.y != 0.f) << r;
        h2 |= (unsigned)(v.z != 0.f) << r;
        h3 |= (unsigned)(v.w != 0.f) << r;
      }
    }
  } else if (mc < M_EDGES) {
    for (int r = 0; r < 32; ++r) {
      const int n = n0 + r;
      if (n < N_NODES) {
        const float* row = H + (size_t)n * M_EDGES;
        if (mc + 0 < M_EDGES) h0 |= (unsigned)(row[mc + 0] != 0.f) << r;
        if (mc + 1 < M_EDGES) h1 |= (unsigned)(row[mc + 1] != 0.f) << r;
        if (mc + 2 < M_EDGES) h2 |= (unsigned)(row[mc + 2] != 0.f) << r;
        if (mc + 3 < M_EDGES) h3 |= (unsigned)(row[mc + 3] != 0.f) << r;
      }
    }
  }
  unsigned* hp = HTb32 + ((size_t)g * MPAD + mc) * 2 + half;  // u64 half (LE)
  hp[0] = h0; hp[2] = h1; hp[4] = h2; hp[6] = h3;
}

// ---------------------------------------------------------------- bt: bit-transpose HTb -> Hb
__global__ __launch_bounds__(256) void bt_kernel(const u64* __restrict__ HTb,
                                                 u64* __restrict__ Hb) {
  const int t = threadIdx.x;
  const int w = t >> 6, l = t & 63;
  const int id = blockIdx.x * 4 + w;
  const int nw = id % NW;
  const int mw = id / NW;
  const u64 word = HTb[(size_t)nw * MPAD + mw * 64 + l];
  u64 out = 0;
  for (int r = 0; r < 64; ++r) {
    const u64 mask = __ballot(((word >> r) & 1ull) != 0);
    if (l == r) out = mask;
  }
  Hb[(size_t)mw * NPAD + nw * 64 + l] = out;
}

// ---------------------------------------------------------------- deg
__global__ __launch_bounds__(256) void deg_kernel(const u64* __restrict__ Hb,
                                                  const u64* __restrict__ HTb,
                                                  float* __restrict__ inv_de,
                                                  float* __restrict__ inv_dv) {
  const int g = blockIdx.x * 256 + threadIdx.x;
  if (g < MPAD) {
    int c = 0;
    for (int nw = 0; nw < NW; ++nw) c += __popcll(HTb[(size_t)nw * MPAD + g]);
    inv_de[g] = 1.f / fmaxf((float)c, 1.f);
  } else if (g < MPAD + NPAD) {
    const int n = g - MPAD;
    int c = 0;
#pragma unroll
    for (int mw = 0; mw < MW; ++mw) c += __popcll(Hb[(size_t)mw * NPAD + n]);
    inv_dv[n] = 1.f / fmaxf((float)c, 1.f);
  }
}

// ---------------------------------------------------------------- gemmA: partialA[s] = bf16(x^T @ H)  (r12-proven)
__global__ __launch_bounds__(256) void gemmA_kernel(const unsigned short* __restrict__ xpb,
                                                    const u64* __restrict__ HTb,
                                                    unsigned short* __restrict__ partial) {
  __shared__ char lds[2][16384];
  const int t = threadIdx.x;
  const int w = t >> 6, l = t & 63;
  const int lr = l & 15, lg = l >> 4;
  const int shl8 = lg * 8;
  const int wgid = blockIdx.x;
  const int mchunk = wgid >> 6;
  const int sj = wgid & 63;
  const int s = sj >> 2, jb = sj & 3;
  const int m0 = mchunk * 256 + w * 64;
  const int j0 = jb * 64;

  f32x4 acc[4][4] = {};
  const u64* bbase = HTb + (size_t)(s * 20) * MPAD + m0 + lr;
  const char* xb = (const char*)xpb;
  const int n8b = s * 160;
  const int sj0 = j0 + w * 16 + lr;

  u64 b00, b01, b02, b03, b04, b05, b06, b07;
  u64 b10, b11, b12, b13, b14, b15, b16, b17;

#define GA_LOADB(S, st_) do {                                                  \
    const u64* bp_ = bbase + (size_t)(st_) * 2 * MPAD;                         \
    b##S##0 = bp_[0]; b##S##1 = bp_[16]; b##S##2 = bp_[32]; b##S##3 = bp_[48]; \
    const u64* bq_ = bp_ + MPAD;                                               \
    b##S##4 = bq_[0]; b##S##5 = bq_[16]; b##S##6 = bq_[32]; b##S##7 = bq_[48]; \
  } while (0)

#define GA_STAGE(buf, st_) do {                                                \
    const size_t r0_ = (size_t)(n8b + (st_) * 16 + lg) * 256 + sj0;            \
    stage16(xb + (r0_) * 16,              &lds[buf][(w) * 1024 + l * 16]);     \
    stage16(xb + (r0_ + 4 * 256) * 16,    &lds[buf][(4 + w) * 1024 + l * 16]); \
    stage16(xb + (r0_ + 8 * 256) * 16,    &lds[buf][(8 + w) * 1024 + l * 16]); \
    stage16(xb + (r0_ + 12 * 256) * 16,   &lds[buf][(12 + w) * 1024 + l * 16]);\
  } while (0)

#define GA_JG(jg, BW) do {                                                     \
    const unsigned wlo_ = (unsigned)(BW), whi_ = (unsigned)((BW) >> 32);       \
    const bf16x8 e0_ = expand8((wlo_ >> shl8) & 255u);                         \
    const bf16x8 e1_ = expand8((whi_ >> shl8) & 255u);                         \
    acc[0][jg] = MFMA16(A00_, e0_, acc[0][jg]);                                \
    acc[1][jg] = MFMA16(A10_, e0_, acc[1][jg]);                                \
    acc[2][jg] = MFMA16(A20_, e0_, acc[2][jg]);                                \
    acc[3][jg] = MFMA16(A30_, e0_, acc[3][jg]);                                \
    acc[0][jg] = MFMA16(A01_, e1_, acc[0][jg]);                                \
    acc[1][jg] = MFMA16(A11_, e1_, acc[1][jg]);                                \
    acc[2][jg] = MFMA16(A21_, e1_, acc[2][jg]);                                \
    acc[3][jg] = MFMA16(A31_, e1_, acc[3][jg]);                                \
  } while (0)

#define GA_COMP(buf, h, W0, W1, W2, W3) do {                                   \
    const char* L_ = &lds[buf][(h) * 8192];                                    \
    const bf16x8 A00_ = *(const bf16x8*)(L_ + l * 16 + 0);                     \
    const bf16x8 A10_ = *(const bf16x8*)(L_ + l * 16 + 1024);                  \
    const bf16x8 A20_ = *(const bf16x8*)(L_ + l * 16 + 2048);                  \
    const bf16x8 A30_ = *(const bf16x8*)(L_ + l * 16 + 3072);                  \
    const bf16x8 A01_ = *(const bf16x8*)(L_ + l * 16 + 4096);                  \
    const bf16x8 A11_ = *(const bf16x8*)(L_ + l * 16 + 5120);                  \
    const bf16x8 A21_ = *(const bf16x8*)(L_ + l * 16 + 6144);                  \
    const bf16x8 A31_ = *(const bf16x8*)(L_ + l * 16 + 7168);                  \
    GA_JG(0, W0); GA_JG(1, W1); GA_JG(2, W2); GA_JG(3, W3);                    \
  } while (0)

  GA_LOADB(0, 0);
  GA_STAGE(0, 0);
  for (int st = 0; st < 10; st += 2) {
    const int n1 = (st + 1 < 10) ? st + 1 : 9;
    GA_LOADB(1, n1); GA_STAGE(1, n1);
    asm volatile("s_waitcnt vmcnt(12)" ::: "memory");
    __builtin_amdgcn_s_barrier();
    GA_COMP(0, 0, b00, b01, b02, b03);
    GA_COMP(0, 1, b04, b05, b06, b07);
    __builtin_amdgcn_s_barrier();
    const int n2 = (st + 2 < 10) ? st + 2 : 9;
    GA_LOADB(0, n2); GA_STAGE(0, n2);
    asm volatile("s_waitcnt vmcnt(12)" ::: "memory");
    __builtin_amdgcn_s_barrier();
    GA_COMP(1, 0, b10, b11, b12, b13);
    GA_COMP(1, 1, b14, b15, b16, b17);
    __builtin_amdgcn_s_barrier();
  }
#undef GA_LOADB
#undef GA_STAGE
#undef GA_JG
#undef GA_COMP

  unsigned short* pp = partial + (size_t)s * (DIN * MPAD);
#pragma unroll
  for (int fr = 0; fr < 4; ++fr)
#pragma unroll
    for (int r = 0; r < 4; ++r) {
      const int j = j0 + fr * 16 + lg * 4 + r;
#pragma unroll
      for (int jg = 0; jg < 4; ++jg)
        pp[(size_t)j * MPAD + m0 + jg * 16 + lr] = f2b(acc[fr][jg][r]);
    }
}

// ---------------------------------------------------------------- reduceA (bf16 partials)
__global__ __launch_bounds__(256) void reduceA_kernel(const unsigned short* __restrict__ partial,
                                                      const float* __restrict__ inv_de,
                                                      unsigned short* __restrict__ t2p) {
  const int t = threadIdx.x;
  const int m = blockIdx.x * 256 + t;
  const int jc = blockIdx.y * 16;
  const float e = inv_de[m];
  unsigned short* ob = t2p + ((size_t)(m >> 3) * 256) * 8 + (m & 7);
  for (int jj = 0; jj < 16; ++jj) {
    const int j = jc + jj;
    const unsigned short* p = partial + (size_t)j * MPAD + m;
    float s = 0.f;
#pragma unroll
    for (int sp = 0; sp < SPLITS; ++sp) s += b2f(p[(size_t)sp * (DIN * MPAD)]);
    ob[(size_t)j * 8] = f2b(s * e);
  }
}

// ---------------------------------------------------------------- gemmB: partialB[s] = bf16(H @ T2)  (r12-proven)
__global__ __launch_bounds__(256) void gemmB_kernel(const unsigned short* __restrict__ t2p,
                                                    const u64* __restrict__ Hb,
                                                    unsigned short* __restrict__ partialB) {
  __shared__ char lds[2][16384];
  const int t = threadIdx.x;
  const int w = t >> 6, l = t & 63;
  const int lr = l & 15, lg = l >> 4;
  const int shl8 = lg * 8;
  const int wgid = blockIdx.x;
  const int nchunk = wgid >> 4;
  const int sj = wgid & 15;
  const int s = sj >> 2, jb = sj & 3;
  const int n0 = nchunk * 256 + w * 64;
  const int j0 = jb * 64;

  f32x4 acc[4][4] = {};
  const u64* abase = Hb + (size_t)(s * 20) * NPAD + n0 + lr;
  const char* tb = (const char*)t2p;
  const int m8b = s * 160;
  const int sj0 = j0 + w * 16 + lr;

  u64 a00, a01, a02, a03, a04, a05, a06, a07;
  u64 a10, a11, a12, a13, a14, a15, a16, a17;

#define GB_LOADA(S, st_) do {                                                  \
    const u64* ap_ = abase + (size_t)(st_) * 2 * NPAD;                         \
    a##S##0 = ap_[0]; a##S##1 = ap_[16]; a##S##2 = ap_[32]; a##S##3 = ap_[48]; \
    const u64* aq_ = ap_ + NPAD;                                               \
    a##S##4 = aq_[0]; a##S##5 = aq_[16]; a##S##6 = aq_[32]; a##S##7 = aq_[48]; \
  } while (0)

#define GB_STAGE(buf, st_) do {                                                \
    const size_t r0_ = (size_t)(m8b + (st_) * 16 + lg) * 256 + sj0;            \
    stage16(tb + (r0_) * 16,              &lds[buf][(w) * 1024 + l * 16]);     \
    stage16(tb + (r0_ + 4 * 256) * 16,    &lds[buf][(4 + w) * 1024 + l * 16]); \
    stage16(tb + (r0_ + 8 * 256) * 16,    &lds[buf][(8 + w) * 1024 + l * 16]); \
    stage16(tb + (r0_ + 12 * 256) * 16,   &lds[buf][(12 + w) * 1024 + l * 16]);\
  } while (0)

#define GB_FR(fr, AW) do {                                                     \
    const unsigned wlo_ = (unsigned)(AW), whi_ = (unsigned)((AW) >> 32);       \
    const bf16x8 e0_ = expand8((wlo_ >> shl8) & 255u);                         \
    const bf16x8 e1_ = expand8((whi_ >> shl8) & 255u);                         \
    acc[fr][0] = MFMA16(e0_, B00_, acc[fr][0]);                                \
    acc[fr][1] = MFMA16(e0_, B10_, acc[fr][1]);                                \
    acc[fr][2] = MFMA16(e0_, B20_, acc[fr][2]);                                \
    acc[fr][3] = MFMA16(e0_, B30_, acc[fr][3]);                                \
    acc[fr][0] = MFMA16(e1_, B01_, acc[fr][0]);                                \
    acc[fr][1] = MFMA16(e1_, B11_, acc[fr][1]);                                \
    acc[fr][2] = MFMA16(e1_, B21_, acc[fr][2]);                                \
    acc[fr][3] = MFMA16(e1_, B31_, acc[fr][3]);                                \
  } while (0)

#define GB_COMP(buf, h, W0, W1, W2, W3) do {                                   \
    const char* L_ = &lds[buf][(h) * 8192];                                    \
    const bf16x8 B00_ = *(const bf16x8*)(L_ + l * 16 + 0);                     \
    const bf16x8 B10_ = *(const bf16x8*)(L_ + l * 16 + 1024);                  \
    const bf16x8 B20_ = *(const bf16x8*)(L_ + l * 16 + 2048);                  \
    const bf16x8 B30_ = *(const bf16x8*)(L_ + l * 16 + 3072);                  \
    const bf16x8 B01_ = *(const bf16x8*)(L_ + l * 16 + 4096);                  \
    const bf16x8 B11_ = *(const bf16x8*)(L_ + l * 16 + 5120);                  \
    const bf16x8 B21_ = *(const bf16x8*)(L_ + l * 16 + 6144);                  \
    const bf16x8 B31_ = *(const bf16x8*)(L_ + l * 16 + 7168);                  \
    GB_FR(0, W0); GB_FR(1, W1); GB_FR(2, W2); GB_FR(3, W3);                    \
  } while (0)

  GB_LOADA(0, 0);
  GB_STAGE(0, 0);
  for (int st = 0; st < 10; st += 2) {
    const int n1 = (st + 1 < 10) ? st + 1 : 9;
    GB_LOADA(1, n1); GB_STAGE(1, n1);
    asm volatile("s_waitcnt vmcnt(12)" ::: "memory");
    __builtin_amdgcn_s_barrier();
    GB_COMP(0, 0, a00, a01, a02, a03);
    GB_COMP(0, 1, a04, a05, a06, a07);
    __builtin_amdgcn_s_barrier();
    const int n2 = (st + 2 < 10) ? st + 2 : 9;
    GB_LOADA(0, n2); GB_STAGE(0, n2);
    asm volatile("s_waitcnt vmcnt(12)" ::: "memory");
    __builtin_amdgcn_s_barrier();
    GB_COMP(1, 0, a10, a11, a12, a13);
    GB_COMP(1, 1, a14, a15, a16, a17);
    __builtin_amdgcn_s_barrier();
  }
#undef GB_LOADA
#undef GB_STAGE
#undef GB_FR
#undef GB_COMP

  unsigned short* pp = partialB + (size_t)s * ((size_t)NPAD * DIN);
#pragma unroll
  for (int fr = 0; fr < 4; ++fr) {
#pragma unroll
    for (int r = 0; r < 4; ++r) {
      const int n = n0 + fr * 16 + lg * 4 + r;
#pragma unroll
      for (int jg = 0; jg < 4; ++jg)
        pp[(size_t)n * DIN + j0 + jg * 16 + lr] = f2b(acc[fr][jg][r]);
    }
  }
}

// ---------------------------------------------------------------- gemmC2 v2 (r12-proven): fused reduceB + [T3|x]@WT + LN
__global__ __launch_bounds__(512) void gemmC2_kernel(const unsigned short* __restrict__ partialB,
                                                     const float* __restrict__ inv_dv,
                                                     const float* __restrict__ x,
                                                     const unsigned short* __restrict__ wtpb,
                                                     const float* __restrict__ gamma,
                                                     const float* __restrict__ beta,
                                                     float* __restrict__ out) {
  __shared__ char ldsA[65536];        // A tile: 64 rows x 512 k bf16 (1024B rows, xor-swz)
  __shared__ float lnred[2][64][8];
  const int t = threadIdx.x;
  const int w = t >> 6, l = t & 63;
  const int lr = l & 15, lg = l >> 4;
  const int n0 = blockIdx.x * 64;

  // Phase 1: T3 tile = bf16((sum_sp partialB) * inv_dv) -> ldsA k<256
  {
    const int k8 = t & 31;
    const int rb = t >> 5;
#pragma unroll
    for (int pass = 0; pass < 4; ++pass) {
      const int r = pass * 16 + rb;
      const size_t base = (size_t)(n0 + r) * 256 + k8 * 8;
      float sum[8] = {0.f, 0.f, 0.f, 0.f, 0.f, 0.f, 0.f, 0.f};
#pragma unroll
      for (int sp = 0; sp < SPLITSB; ++sp) {
        const bf16x8 v = *(const bf16x8*)(partialB + (size_t)sp * ((size_t)NPAD * DIN) + base);
#pragma unroll
        for (int i = 0; i < 8; ++i) sum[i] += b2f((unsigned short)v[i]);
      }
      const float dv = inv_dv[n0 + r];
      union { unsigned u[4]; bf16x8 v; } o;
#pragma unroll
      for (int p = 0; p < 4; ++p)
        o.u[p] = (unsigned)f2b(sum[2 * p] * dv) | ((unsigned)f2b(sum[2 * p + 1] * dv) << 16);
      *(bf16x8*)(ldsA + r * 1024 + ((k8 * 16) ^ ((r & 7) << 4))) = o.v;
    }
  }
  // Phase 2: x tile -> ldsA k in [256,512)
  {
    const int c4 = t & 63;
    const int rb = t >> 6;
#pragma unroll
    for (int pass = 0; pass < 8; ++pass) {
      const int r = pass * 8 + rb;
      float4 v = make_float4(0.f, 0.f, 0.f, 0.f);
      if (n0 + r < N_NODES) v = *(const float4*)(x + (size_t)(n0 + r) * DIN + c4 * 4);
      const unsigned u0 = (unsigned)f2b(v.x) | ((unsigned)f2b(v.y) << 16);
      const unsigned u1 = (unsigned)f2b(v.z) | ((unsigned)f2b(v.w) << 16);
      const int byte0 = 512 + c4 * 8;
      const int off = ((byte0 & ~15) ^ ((r & 7) << 4)) + (byte0 & 8);
      *(uint2*)(ldsA + r * 1024 + off) = make_uint2(u0, u1);
    }
  }
  __syncthreads();

  f32x4 acc[4][4] = {};
  const int wcol = w * 64;
#pragma unroll 2
  for (int kt = 0; kt < 16; ++kt) {
    bf16x8 bf[4];
#pragma unroll
    for (int jg = 0; jg < 4; ++jg) {
      const int col = wcol + jg * 16 + lr;
      bf[jg] = *(const bf16x8*)(wtpb + (((size_t)(kt * 4 + lg) * 512 + col) << 3));
    }
    const int kbA = kt * 64 + lg * 16;
#pragma unroll
    for (int fr = 0; fr < 4; ++fr) {
      const int row = fr * 16 + lr;
      const bf16x8 af = *(const bf16x8*)(ldsA + row * 1024 + (kbA ^ ((row & 7) << 4)));
#pragma unroll
      for (int jg = 0; jg < 4; ++jg)
        acc[fr][jg] = MFMA16(af, bf[jg], acc[fr][jg]);
    }
  }

#pragma unroll
  for (int fr = 0; fr < 4; ++fr)
#pragma unroll
    for (int r = 0; r < 4; ++r) {
      float s = 0.f, s2 = 0.f;
#pragma unroll
      for (int jg = 0; jg < 4; ++jg) {
        const float v = acc[fr][jg][r];
        s += v; s2 += v * v;
      }
#pragma unroll
      for (int m = 1; m < 16; m <<= 1) {
        s += __shfl_xor(s, m, 64);
        s2 += __shfl_xor(s2, m, 64);
      }
      if (lr == 0) {
        const int row = fr * 16 + lg * 4 + r;
        lnred[0][row][w] = s;
        lnred[1][row][w] = s2;
      }
    }
  __syncthreads();

#pragma unroll
  for (int fr = 0; fr < 4; ++fr) {
#pragma unroll
    for (int r = 0; r < 4; ++r) {
      const int row = fr * 16 + lg * 4 + r;
      float S = 0.f, S2 = 0.f;
#pragma unroll
      for (int ww = 0; ww < 8; ++ww) { S += lnred[0][row][ww]; S2 += lnred[1][row][ww]; }
      const float mu = S * (1.f / 512.f);
      const float rs = rsqrtf(S2 * (1.f / 512.f) - mu * mu + 1e-5f);
      const int gn = n0 + row;
      if (gn < N_NODES) {
#pragma unroll
        for (int jg = 0; jg < 4; ++jg) {
          const int col = wcol + jg * 16 + lr;
          out[(size_t)gn * DOUT + col] = (acc[fr][jg][r] - mu) * rs * gamma[col] + beta[col];
        }
      }
    }
  }
}

// ----------------------------------------------------------------
extern "C" void kernel_launch(void* const* d_in, const int* in_sizes, int n_in,
                              void* d_out, int out_size, void* d_ws, size_t ws_size,
                              hipStream_t stream) {
  (void)in_sizes; (void)n_in; (void)out_size; (void)ws_size;
  const float* x = (const float*)d_in[0];
  const float* H = (const float*)d_in[1];
  const float* Wn = (const float*)d_in[2];
  const float* Wr = (const float*)d_in[3];
  const float* gamma = (const float*)d_in[4];
  const float* beta = (const float*)d_in[5];
  float* out = (float*)d_out;
  char* ws = (char*)d_ws;

  unsigned short* wtpb     = (unsigned short*)(ws + 0);
  u64* Hb                  = (u64*)(ws + 524288);
  u64* HTb                 = (u64*)(ws + 13631488);
  float* inv_de            = (float*)(ws + 26738688);
  float* inv_dv            = (float*)(ws + 26759168);
  unsigned short* xpb      = (unsigned short*)(ws + 26841088);
  unsigned short* partialA = (unsigned short*)(ws + 37326848);
  unsigned short* t2p      = (unsigned short*)(ws + 79269888);
  unsigned short* partialB = (unsigned short*)(ws + 81891328);

  prep_kernel<<<dim3(1024), dim3(256), 0, stream>>>(Wn, Wr, wtpb);
  xt_kernel<<<dim3(2560), dim3(256), 0, stream>>>(x, xpb);
  pack_kernel<<<dim3(640, 5), dim3(256), 0, stream>>>(H, (unsigned*)HTb);
  bt_kernel<<<dim3(6400), dim3(256), 0, stream>>>(HTb, Hb);
  deg_kernel<<<dim3(100), dim3(256), 0, stream>>>(Hb, HTb, inv_de, inv_dv);
  gemmA_kernel<<<dim3(1280), dim3(256), 0, stream>>>(xpb, HTb, partialA);
  reduceA_kernel<<<dim3(20, 16), dim3(256), 0, stream>>>(partialA, inv_de, t2p);
  gemmB_kernel<<<dim3(1280), dim3(256), 0, stream>>>(t2p, Hb, partialB);
  gemmC2_kernel<<<dim3(313), dim3(512), 0, stream>>>(partialB, inv_dv, x, wtpb,
                                                     gamma, beta, out);
}

// Round 15
// 321.163 us; speedup vs baseline: 1.6061x; 1.0098x over previous
//
#include <hip/hip_runtime.h>

// HypergraphConv: out = LN( (H diag(1/d_e) H^T x) / d_v @ W_node + x @ W_res )
//
// Round-15: r14 (= r12-proven pipeline + pack v5 geometry) + pack v6:
// branch-hoisted fast path. The per-row n<N_NODES check inside the row loop
// serialized the float4 loads (~4.4 TB/s effective); for full row-groups
// (638/640) the check hoists out and 32 independent loads pipeline deeply.
// Everything else identical to round-14.
//
// Workspace (bytes):
//   wtpb     bf16 frag img 512x512 @ 0       (524,288)
//   Hb       u64  80x20480     @ 524,288     (13,107,200)
//   HTb      u64  320x5120     @ 13,631,488  (13,107,200)
//   inv_de   f32  5120         @ 26,738,688  (20,480)
//   inv_dv   f32  20480        @ 26,759,168  (81,920)
//   xpb      img  2560x256x16B @ 26,841,088  (10,485,760)
//   partialA bf16 16x256x5120  @ 37,326,848  (41,943,040)
//   t2p      img  640x256x16B  @ 79,269,888  (2,621,440)
//   partialB bf16 4x20480x256  @ 81,891,328  (41,943,040)  total ~124 MB

#define N_NODES 20000
#define M_EDGES 5000
#define MPAD    5120
#define NPAD    20480
#define NW      320
#define MW      80
#define DIN     256
#define DOUT    512
#define SPLITS  16
#define SPLITSB 4

typedef short bf16x8 __attribute__((ext_vector_type(8)));
typedef float f32x4 __attribute__((ext_vector_type(4)));
typedef unsigned long long u64;

#define MFMA16(A, B, C) __builtin_amdgcn_mfma_f32_16x16x32_bf16((A), (B), (C), 0, 0, 0)

__device__ __forceinline__ unsigned short f2b(float f) {
  unsigned u = __builtin_bit_cast(unsigned, f);
  return (unsigned short)((u + 0x7FFFu + ((u >> 16) & 1u)) >> 16);  // RNE
}

__device__ __forceinline__ float b2f(unsigned short b) {
  return __builtin_bit_cast(float, ((unsigned)b) << 16);
}

__device__ __forceinline__ void stage16(const void* g, void* l) {
  __builtin_amdgcn_global_load_lds(
      (const __attribute__((address_space(1))) unsigned int*)g,
      (__attribute__((address_space(3))) unsigned int*)l, 16, 0, 0);
}

// 8 bits -> 8 bf16 {0,1}
__device__ __forceinline__ bf16x8 expand8(unsigned b) {
  union { unsigned u[4]; bf16x8 v; } r;
  const unsigned t = b | (b << 15);
  r.u[0] = (t & 0x00010001u) * 0x3F80u;
  r.u[1] = ((t >> 2) & 0x00010001u) * 0x3F80u;
  r.u[2] = ((t >> 4) & 0x00010001u) * 0x3F80u;
  r.u[3] = ((t >> 6) & 0x00010001u) * 0x3F80u;
  return r.v;
}

// ---------------------------------------------------------------- prep: wtpb frag image
__global__ __launch_bounds__(256) void prep_kernel(const float* __restrict__ Wn,
                                                   const float* __restrict__ Wr,
                                                   unsigned short* __restrict__ wtpb) {
  const int q = blockIdx.x * 256 + threadIdx.x;  // < 262144
  const int j = q >> 9, k = q & 511;
  const float v = (k < 256) ? Wn[(size_t)k * 512 + j] : Wr[(size_t)(k - 256) * 512 + j];
  wtpb[(((size_t)(k >> 3) * 512 + j) << 3) + (k & 7)] = f2b(v);
}

// ---------------------------------------------------------------- xt
__global__ __launch_bounds__(256) void xt_kernel(const float* __restrict__ x,
                                                 unsigned short* __restrict__ xpb) {
  const int j = threadIdx.x;
  const int n8 = blockIdx.x;
  union { unsigned u[4]; bf16x8 v; } o;
#pragma unroll
  for (int p = 0; p < 4; ++p) {
    const int n = n8 * 8 + 2 * p;
    const float v0 = (n < N_NODES) ? x[(size_t)n * DIN + j] : 0.f;
    const float v1 = (n + 1 < N_NODES) ? x[(size_t)(n + 1) * DIN + j] : 0.f;
    o.u[p] = (unsigned)f2b(v0) | ((unsigned)f2b(v1) << 16);
  }
  *(bf16x8*)(xpb + ((size_t)n8 * 256 + j) * 8) = o.v;
}

// ---------------------------------------------------------------- pack v6: 32-row groups, branch-hoisted fast path
// grid (640, 5): block = 32 rows x 1024 cols. Thread owns 4 fixed cols;
// full groups run a check-free unrolled loop (32 loads pipeline deeply).
__global__ __launch_bounds__(256) void pack_kernel(const float* __restrict__ H,
                                                   unsigned* __restrict__ HTb32) {
  const int t = threadIdx.x;
  const int gg = blockIdx.x;       // 0..639 (32-row group)
  const int h = blockIdx.y;        // 0..4   (1024-col group)
  const int g = gg >> 1, half = gg & 1;
  const int n0 = gg * 32;
  const int mc = h * 1024 + 4 * t; // this thread's 4 columns
  unsigned h0 = 0, h1 = 0, h2 = 0, h3 = 0;
  if (mc + 3 < M_EDGES) {
    const float* col = H + mc;
    if (n0 + 32 <= N_NODES) {
      // fast path: no per-row bounds check -> loads batch
#pragma unroll
      for (int r = 0; r < 32; ++r) {
        const float4 v = *(const float4*)(col + (size_t)(n0 + r) * M_EDGES);
        h0 |= (unsigned)(v.x != 0.f) << r;
        h1 |= (unsigned)(v.y != 0.f) << r;
        h2 |= (unsigned)(v.z != 0.f) << r;
        h3 |= (unsigned)(v.w != 0.f) << r;
      }
    } else {
      for (int r = 0; r < 32; ++r) {
        const int n = n0 + r;
        if (n < N_NODES) {
          const float4 v = *(const float4*)(col + (size_t)n * M_EDGES);
          h0 |= (unsigned)(v.x != 0.f) << r;
          h1 |= (unsigned)(v.y != 0.f) << r;
          h2 |= (unsigned)(v.z != 0.f) << r;
          h3 |= (unsigned)(v.w != 0.f) << r;
        }
      }
    }
  } else if (mc < M_EDGES) {
    for (int r = 0; r < 32; ++r) {
      const int n = n0 + r;
      if (n < N_NODES) {
        const float* row = H + (size_t)n * M_EDGES;
        if (mc + 0 < M_EDGES) h0 |= (unsigned)(row[mc + 0] != 0.f) << r;
        if (mc + 1 < M_EDGES) h1 |= (unsigned)(row[mc + 1] != 0.f) << r;
        if (mc + 2 < M_EDGES) h2 |= (unsigned)(row[mc + 2] != 0.f) << r;
        if (mc + 3 < M_EDGES) h3 |= (unsigned)(row[mc + 3] != 0.f) << r;
      }
    }
  }
  unsigned* hp = HTb32 + ((size_t)g * MPAD + mc) * 2 + half;  // u64 half (LE)
  hp[0] = h0; hp[2] = h1; hp[4] = h2; hp[6] = h3;
}

// ---------------------------------------------------------------- bt: bit-transpose HTb -> Hb
__global__ __launch_bounds__(256) void bt_kernel(const u64* __restrict__ HTb,
                                                 u64* __restrict__ Hb) {
  const int t = threadIdx.x;
  const int w = t >> 6, l = t & 63;
  const int id = blockIdx.x * 4 + w;
  const int nw = id % NW;
  const int mw = id / NW;
  const u64 word = HTb[(size_t)nw * MPAD + mw * 64 + l];
  u64 out = 0;
  for (int r = 0; r < 64; ++r) {
    const u64 mask = __ballot(((word >> r) & 1ull) != 0);
    if (l == r) out = mask;
  }
  Hb[(size_t)mw * NPAD + nw * 64 + l] = out;
}

// ---------------------------------------------------------------- deg
__global__ __launch_bounds__(256) void deg_kernel(const u64* __restrict__ Hb,
                                                  const u64* __restrict__ HTb,
                                                  float* __restrict__ inv_de,
                                                  float* __restrict__ inv_dv) {
  const int g = blockIdx.x * 256 + threadIdx.x;
  if (g < MPAD) {
    int c = 0;
    for (int nw = 0; nw < NW; ++nw) c += __popcll(HTb[(size_t)nw * MPAD + g]);
    inv_de[g] = 1.f / fmaxf((float)c, 1.f);
  } else if (g < MPAD + NPAD) {
    const int n = g - MPAD;
    int c = 0;
#pragma unroll
    for (int mw = 0; mw < MW; ++mw) c += __popcll(Hb[(size_t)mw * NPAD + n]);
    inv_dv[n] = 1.f / fmaxf((float)c, 1.f);
  }
}

// ---------------------------------------------------------------- gemmA: partialA[s] = bf16(x^T @ H)  (r12-proven)
__global__ __launch_bounds__(256) void gemmA_kernel(const unsigned short* __restrict__ xpb,
                                                    const u64* __restrict__ HTb,
                                                    unsigned short* __restrict__ partial) {
  __shared__ char lds[2][16384];
  const int t = threadIdx.x;
  const int w = t >> 6, l = t & 63;
  const int lr = l & 15, lg = l >> 4;
  const int shl8 = lg * 8;
  const int wgid = blockIdx.x;
  const int mchunk = wgid >> 6;
  const int sj = wgid & 63;
  const int s = sj >> 2, jb = sj & 3;
  const int m0 = mchunk * 256 + w * 64;
  const int j0 = jb * 64;

  f32x4 acc[4][4] = {};
  const u64* bbase = HTb + (size_t)(s * 20) * MPAD + m0 + lr;
  const char* xb = (const char*)xpb;
  const int n8b = s * 160;
  const int sj0 = j0 + w * 16 + lr;

  u64 b00, b01, b02, b03, b04, b05, b06, b07;
  u64 b10, b11, b12, b13, b14, b15, b16, b17;

#define GA_LOADB(S, st_) do {                                                  \
    const u64* bp_ = bbase + (size_t)(st_) * 2 * MPAD;                         \
    b##S##0 = bp_[0]; b##S##1 = bp_[16]; b##S##2 = bp_[32]; b##S##3 = bp_[48]; \
    const u64* bq_ = bp_ + MPAD;                                               \
    b##S##4 = bq_[0]; b##S##5 = bq_[16]; b##S##6 = bq_[32]; b##S##7 = bq_[48]; \
  } while (0)

#define GA_STAGE(buf, st_) do {                                                \
    const size_t r0_ = (size_t)(n8b + (st_) * 16 + lg) * 256 + sj0;            \
    stage16(xb + (r0_) * 16,              &lds[buf][(w) * 1024 + l * 16]);     \
    stage16(xb + (r0_ + 4 * 256) * 16,    &lds[buf][(4 + w) * 1024 + l * 16]); \
    stage16(xb + (r0_ + 8 * 256) * 16,    &lds[buf][(8 + w) * 1024 + l * 16]); \
    stage16(xb + (r0_ + 12 * 256) * 16,   &lds[buf][(12 + w) * 1024 + l * 16]);\
  } while (0)

#define GA_JG(jg, BW) do {                                                     \
    const unsigned wlo_ = (unsigned)(BW), whi_ = (unsigned)((BW) >> 32);       \
    const bf16x8 e0_ = expand8((wlo_ >> shl8) & 255u);                         \
    const bf16x8 e1_ = expand8((whi_ >> shl8) & 255u);                         \
    acc[0][jg] = MFMA16(A00_, e0_, acc[0][jg]);                                \
    acc[1][jg] = MFMA16(A10_, e0_, acc[1][jg]);                                \
    acc[2][jg] = MFMA16(A20_, e0_, acc[2][jg]);                                \
    acc[3][jg] = MFMA16(A30_, e0_, acc[3][jg]);                                \
    acc[0][jg] = MFMA16(A01_, e1_, acc[0][jg]);                                \
    acc[1][jg] = MFMA16(A11_, e1_, acc[1][jg]);                                \
    acc[2][jg] = MFMA16(A21_, e1_, acc[2][jg]);                                \
    acc[3][jg] = MFMA16(A31_, e1_, acc[3][jg]);                                \
  } while (0)

#define GA_COMP(buf, h, W0, W1, W2, W3) do {                                   \
    const char* L_ = &lds[buf][(h) * 8192];                                    \
    const bf16x8 A00_ = *(const bf16x8*)(L_ + l * 16 + 0);                     \
    const bf16x8 A10_ = *(const bf16x8*)(L_ + l * 16 + 1024);                  \
    const bf16x8 A20_ = *(const bf16x8*)(L_ + l * 16 + 2048);                  \
    const bf16x8 A30_ = *(const bf16x8*)(L_ + l * 16 + 3072);                  \
    const bf16x8 A01_ = *(const bf16x8*)(L_ + l * 16 + 4096);                  \
    const bf16x8 A11_ = *(const bf16x8*)(L_ + l * 16 + 5120);                  \
    const bf16x8 A21_ = *(const bf16x8*)(L_ + l * 16 + 6144);                  \
    const bf16x8 A31_ = *(const bf16x8*)(L_ + l * 16 + 7168);                  \
    GA_JG(0, W0); GA_JG(1, W1); GA_JG(2, W2); GA_JG(3, W3);                    \
  } while (0)

  GA_LOADB(0, 0);
  GA_STAGE(0, 0);
  for (int st = 0; st < 10; st += 2) {
    const int n1 = (st + 1 < 10) ? st + 1 : 9;
    GA_LOADB(1, n1); GA_STAGE(1, n1);
    asm volatile("s_waitcnt vmcnt(12)" ::: "memory");
    __builtin_amdgcn_s_barrier();
    GA_COMP(0, 0, b00, b01, b02, b03);
    GA_COMP(0, 1, b04, b05, b06, b07);
    __builtin_amdgcn_s_barrier();
    const int n2 = (st + 2 < 10) ? st + 2 : 9;
    GA_LOADB(0, n2); GA_STAGE(0, n2);
    asm volatile("s_waitcnt vmcnt(12)" ::: "memory");
    __builtin_amdgcn_s_barrier();
    GA_COMP(1, 0, b10, b11, b12, b13);
    GA_COMP(1, 1, b14, b15, b16, b17);
    __builtin_amdgcn_s_barrier();
  }
#undef GA_LOADB
#undef GA_STAGE
#undef GA_JG
#undef GA_COMP

  unsigned short* pp = partial + (size_t)s * (DIN * MPAD);
#pragma unroll
  for (int fr = 0; fr < 4; ++fr)
#pragma unroll
    for (int r = 0; r < 4; ++r) {
      const int j = j0 + fr * 16 + lg * 4 + r;
#pragma unroll
      for (int jg = 0; jg < 4; ++jg)
        pp[(size_t)j * MPAD + m0 + jg * 16 + lr] = f2b(acc[fr][jg][r]);
    }
}

// ---------------------------------------------------------------- reduceA (bf16 partials)
__global__ __launch_bounds__(256) void reduceA_kernel(const unsigned short* __restrict__ partial,
                                                      const float* __restrict__ inv_de,
                                                      unsigned short* __restrict__ t2p) {
  const int t = threadIdx.x;
  const int m = blockIdx.x * 256 + t;
  const int jc = blockIdx.y * 16;
  const float e = inv_de[m];
  unsigned short* ob = t2p + ((size_t)(m >> 3) * 256) * 8 + (m & 7);
  for (int jj = 0; jj < 16; ++jj) {
    const int j = jc + jj;
    const unsigned short* p = partial + (size_t)j * MPAD + m;
    float s = 0.f;
#pragma unroll
    for (int sp = 0; sp < SPLITS; ++sp) s += b2f(p[(size_t)sp * (DIN * MPAD)]);
    ob[(size_t)j * 8] = f2b(s * e);
  }
}

// ---------------------------------------------------------------- gemmB: partialB[s] = bf16(H @ T2)  (r12-proven)
__global__ __launch_bounds__(256) void gemmB_kernel(const unsigned short* __restrict__ t2p,
                                                    const u64* __restrict__ Hb,
                                                    unsigned short* __restrict__ partialB) {
  __shared__ char lds[2][16384];
  const int t = threadIdx.x;
  const int w = t >> 6, l = t & 63;
  const int lr = l & 15, lg = l >> 4;
  const int shl8 = lg * 8;
  const int wgid = blockIdx.x;
  const int nchunk = wgid >> 4;
  const int sj = wgid & 15;
  const int s = sj >> 2, jb = sj & 3;
  const int n0 = nchunk * 256 + w * 64;
  const int j0 = jb * 64;

  f32x4 acc[4][4] = {};
  const u64* abase = Hb + (size_t)(s * 20) * NPAD + n0 + lr;
  const char* tb = (const char*)t2p;
  const int m8b = s * 160;
  const int sj0 = j0 + w * 16 + lr;

  u64 a00, a01, a02, a03, a04, a05, a06, a07;
  u64 a10, a11, a12, a13, a14, a15, a16, a17;

#define GB_LOADA(S, st_) do {                                                  \
    const u64* ap_ = abase + (size_t)(st_) * 2 * NPAD;                         \
    a##S##0 = ap_[0]; a##S##1 = ap_[16]; a##S##2 = ap_[32]; a##S##3 = ap_[48]; \
    const u64* aq_ = ap_ + NPAD;                                               \
    a##S##4 = aq_[0]; a##S##5 = aq_[16]; a##S##6 = aq_[32]; a##S##7 = aq_[48]; \
  } while (0)

#define GB_STAGE(buf, st_) do {                                                \
    const size_t r0_ = (size_t)(m8b + (st_) * 16 + lg) * 256 + sj0;            \
    stage16(tb + (r0_) * 16,              &lds[buf][(w) * 1024 + l * 16]);     \
    stage16(tb + (r0_ + 4 * 256) * 16,    &lds[buf][(4 + w) * 1024 + l * 16]); \
    stage16(tb + (r0_ + 8 * 256) * 16,    &lds[buf][(8 + w) * 1024 + l * 16]); \
    stage16(tb + (r0_ + 12 * 256) * 16,   &lds[buf][(12 + w) * 1024 + l * 16]);\
  } while (0)

#define GB_FR(fr, AW) do {                                                     \
    const unsigned wlo_ = (unsigned)(AW), whi_ = (unsigned)((AW) >> 32);       \
    const bf16x8 e0_ = expand8((wlo_ >> shl8) & 255u);                         \
    const bf16x8 e1_ = expand8((whi_ >> shl8) & 255u);                         \
    acc[fr][0] = MFMA16(e0_, B00_, acc[fr][0]);                                \
    acc[fr][1] = MFMA16(e0_, B10_, acc[fr][1]);                                \
    acc[fr][2] = MFMA16(e0_, B20_, acc[fr][2]);                                \
    acc[fr][3] = MFMA16(e0_, B30_, acc[fr][3]);                                \
    acc[fr][0] = MFMA16(e1_, B01_, acc[fr][0]);                                \
    acc[fr][1] = MFMA16(e1_, B11_, acc[fr][1]);                                \
    acc[fr][2] = MFMA16(e1_, B21_, acc[fr][2]);                                \
    acc[fr][3] = MFMA16(e1_, B31_, acc[fr][3]);                                \
  } while (0)

#define GB_COMP(buf, h, W0, W1, W2, W3) do {                                   \
    const char* L_ = &lds[buf][(h) * 8192];                                    \
    const bf16x8 B00_ = *(const bf16x8*)(L_ + l * 16 + 0);                     \
    const bf16x8 B10_ = *(const bf16x8*)(L_ + l * 16 + 1024);                  \
    const bf16x8 B20_ = *(const bf16x8*)(L_ + l * 16 + 2048);                  \
    const bf16x8 B30_ = *(const bf16x8*)(L_ + l * 16 + 3072);                  \
    const bf16x8 B01_ = *(const bf16x8*)(L_ + l * 16 + 4096);                  \
    const bf16x8 B11_ = *(const bf16x8*)(L_ + l * 16 + 5120);                  \
    const bf16x8 B21_ = *(const bf16x8*)(L_ + l * 16 + 6144);                  \
    const bf16x8 B31_ = *(const bf16x8*)(L_ + l * 16 + 7168);                  \
    GB_FR(0, W0); GB_FR(1, W1); GB_FR(2, W2); GB_FR(3, W3);                    \
  } while (0)

  GB_LOADA(0, 0);
  GB_STAGE(0, 0);
  for (int st = 0; st < 10; st += 2) {
    const int n1 = (st + 1 < 10) ? st + 1 : 9;
    GB_LOADA(1, n1); GB_STAGE(1, n1);
    asm volatile("s_waitcnt vmcnt(12)" ::: "memory");
    __builtin_amdgcn_s_barrier();
    GB_COMP(0, 0, a00, a01, a02, a03);
    GB_COMP(0, 1, a04, a05, a06, a07);
    __builtin_amdgcn_s_barrier();
    const int n2 = (st + 2 < 10) ? st + 2 : 9;
    GB_LOADA(0, n2); GB_STAGE(0, n2);
    asm volatile("s_waitcnt vmcnt(12)" ::: "memory");
    __builtin_amdgcn_s_barrier();
    GB_COMP(1, 0, a10, a11, a12, a13);
    GB_COMP(1, 1, a14, a15, a16, a17);
    __builtin_amdgcn_s_barrier();
  }
#undef GB_LOADA
#undef GB_STAGE
#undef GB_FR
#undef GB_COMP

  unsigned short* pp = partialB + (size_t)s * ((size_t)NPAD * DIN);
#pragma unroll
  for (int fr = 0; fr < 4; ++fr) {
#pragma unroll
    for (int r = 0; r < 4; ++r) {
      const int n = n0 + fr * 16 + lg * 4 + r;
#pragma unroll
      for (int jg = 0; jg < 4; ++jg)
        pp[(size_t)n * DIN + j0 + jg * 16 + lr] = f2b(acc[fr][jg][r]);
    }
  }
}

// ---------------------------------------------------------------- gemmC2 v2 (r12-proven): fused reduceB + [T3|x]@WT + LN
__global__ __launch_bounds__(512) void gemmC2_kernel(const unsigned short* __restrict__ partialB,
                                                     const float* __restrict__ inv_dv,
                                                     const float* __restrict__ x,
                                                     const unsigned short* __restrict__ wtpb,
                                                     const float* __restrict__ gamma,
                                                     const float* __restrict__ beta,
                                                     float* __restrict__ out) {
  __shared__ char ldsA[65536];        // A tile: 64 rows x 512 k bf16 (1024B rows, xor-swz)
  __shared__ float lnred[2][64][8];
  const int t = threadIdx.x;
  const int w = t >> 6, l = t & 63;
  const int lr = l & 15, lg = l >> 4;
  const int n0 = blockIdx.x * 64;

  // Phase 1: T3 tile = bf16((sum_sp partialB) * inv_dv) -> ldsA k<256
  {
    const int k8 = t & 31;
    const int rb = t >> 5;
#pragma unroll
    for (int pass = 0; pass < 4; ++pass) {
      const int r = pass * 16 + rb;
      const size_t base = (size_t)(n0 + r) * 256 + k8 * 8;
      float sum[8] = {0.f, 0.f, 0.f, 0.f, 0.f, 0.f, 0.f, 0.f};
#pragma unroll
      for (int sp = 0; sp < SPLITSB; ++sp) {
        const bf16x8 v = *(const bf16x8*)(partialB + (size_t)sp * ((size_t)NPAD * DIN) + base);
#pragma unroll
        for (int i = 0; i < 8; ++i) sum[i] += b2f((unsigned short)v[i]);
      }
      const float dv = inv_dv[n0 + r];
      union { unsigned u[4]; bf16x8 v; } o;
#pragma unroll
      for (int p = 0; p < 4; ++p)
        o.u[p] = (unsigned)f2b(sum[2 * p] * dv) | ((unsigned)f2b(sum[2 * p + 1] * dv) << 16);
      *(bf16x8*)(ldsA + r * 1024 + ((k8 * 16) ^ ((r & 7) << 4))) = o.v;
    }
  }
  // Phase 2: x tile -> ldsA k in [256,512)
  {
    const int c4 = t & 63;
    const int rb = t >> 6;
#pragma unroll
    for (int pass = 0; pass < 8; ++pass) {
      const int r = pass * 8 + rb;
      float4 v = make_float4(0.f, 0.f, 0.f, 0.f);
      if (n0 + r < N_NODES) v = *(const float4*)(x + (size_t)(n0 + r) * DIN + c4 * 4);
      const unsigned u0 = (unsigned)f2b(v.x) | ((unsigned)f2b(v.y) << 16);
      const unsigned u1 = (unsigned)f2b(v.z) | ((unsigned)f2b(v.w) << 16);
      const int byte0 = 512 + c4 * 8;
      const int off = ((byte0 & ~15) ^ ((r & 7) << 4)) + (byte0 & 8);
      *(uint2*)(ldsA + r * 1024 + off) = make_uint2(u0, u1);
    }
  }
  __syncthreads();

  f32x4 acc[4][4] = {};
  const int wcol = w * 64;
#pragma unroll 2
  for (int kt = 0; kt < 16; ++kt) {
    bf16x8 bf[4];
#pragma unroll
    for (int jg = 0; jg < 4; ++jg) {
      const int col = wcol + jg * 16 + lr;
      bf[jg] = *(const bf16x8*)(wtpb + (((size_t)(kt * 4 + lg) * 512 + col) << 3));
    }
    const int kbA = kt * 64 + lg * 16;
#pragma unroll
    for (int fr = 0; fr < 4; ++fr) {
      const int row = fr * 16 + lr;
      const bf16x8 af = *(const bf16x8*)(ldsA + row * 1024 + (kbA ^ ((row & 7) << 4)));
#pragma unroll
      for (int jg = 0; jg < 4; ++jg)
        acc[fr][jg] = MFMA16(af, bf[jg], acc[fr][jg]);
    }
  }

#pragma unroll
  for (int fr = 0; fr < 4; ++fr)
#pragma unroll
    for (int r = 0; r < 4; ++r) {
      float s = 0.f, s2 = 0.f;
#pragma unroll
      for (int jg = 0; jg < 4; ++jg) {
        const float v = acc[fr][jg][r];
        s += v; s2 += v * v;
      }
#pragma unroll
      for (int m = 1; m < 16; m <<= 1) {
        s += __shfl_xor(s, m, 64);
        s2 += __shfl_xor(s2, m, 64);
      }
      if (lr == 0) {
        const int row = fr * 16 + lg * 4 + r;
        lnred[0][row][w] = s;
        lnred[1][row][w] = s2;
      }
    }
  __syncthreads();

#pragma unroll
  for (int fr = 0; fr < 4; ++fr) {
#pragma unroll
    for (int r = 0; r < 4; ++r) {
      const int row = fr * 16 + lg * 4 + r;
      float S = 0.f, S2 = 0.f;
#pragma unroll
      for (int ww = 0; ww < 8; ++ww) { S += lnred[0][row][ww]; S2 += lnred[1][row][ww]; }
      const float mu = S * (1.f / 512.f);
      const float rs = rsqrtf(S2 * (1.f / 512.f) - mu * mu + 1e-5f);
      const int gn = n0 + row;
      if (gn < N_NODES) {
#pragma unroll
        for (int jg = 0; jg < 4; ++jg) {
          const int col = wcol + jg * 16 + lr;
          out[(size_t)gn * DOUT + col] = (acc[fr][jg][r] - mu) * rs * gamma[col] + beta[col];
        }
      }
    }
  }
}

// ----------------------------------------------------------------
extern "C" void kernel_launch(void* const* d_in, const int* in_sizes, int n_in,
                              void* d_out, int out_size, void* d_ws, size_t ws_size,
                              hipStream_t stream) {
  (void)in_sizes; (void)n_in; (void)out_size; (void)ws_size;
  const float* x = (const float*)d_in[0];
  const float* H = (const float*)d_in[1];
  const float* Wn = (const float*)d_in[2];
  const float* Wr = (const float*)d_in[3];
  const float* gamma = (const float*)d_in[4];
  const float* beta = (const float*)d_in[5];
  float* out = (float*)d_out;
  char* ws = (char*)d_ws;

  unsigned short* wtpb     = (unsigned short*)(ws + 0);
  u64* Hb                  = (u64*)(ws + 524288);
  u64* HTb                 = (u64*)(ws + 13631488);
  float* inv_de            = (float*)(ws + 26738688);
  float* inv_dv            = (float*)(ws + 26759168);
  unsigned short* xpb      = (unsigned short*)(ws + 26841088);
  unsigned short* partialA = (unsigned short*)(ws + 37326848);
  unsigned short* t2p      = (unsigned short*)(ws + 79269888);
  unsigned short* partialB = (unsigned short*)(ws + 81891328);

  prep_kernel<<<dim3(1024), dim3(256), 0, stream>>>(Wn, Wr, wtpb);
  xt_kernel<<<dim3(2560), dim3(256), 0, stream>>>(x, xpb);
  pack_kernel<<<dim3(640, 5), dim3(256), 0, stream>>>(H, (unsigned*)HTb);
  bt_kernel<<<dim3(6400), dim3(256), 0, stream>>>(HTb, Hb);
  deg_kernel<<<dim3(100), dim3(256), 0, stream>>>(Hb, HTb, inv_de, inv_dv);
  gemmA_kernel<<<dim3(1280), dim3(256), 0, stream>>>(xpb, HTb, partialA);
  reduceA_kernel<<<dim3(20, 16), dim3(256), 0, stream>>>(partialA, inv_de, t2p);
  gemmB_kernel<<<dim3(1280), dim3(256), 0, stream>>>(t2p, Hb, partialB);
  gemmC2_kernel<<<dim3(313), dim3(512), 0, stream>>>(partialB, inv_dv, x, wtpb,
                                                     gamma, beta, out);
}

// Round 16
// 315.368 us; speedup vs baseline: 1.6356x; 1.0184x over previous
//
#include <hip/hip_runtime.h>

// HypergraphConv: out = LN( (H diag(1/d_e) H^T x) / d_v @ W_node + x @ W_res )
//
// Round-16: r15 + pack v7 = DRAM-page-coalesced block order. Grid linearized
// to 3200 1-D with h = wgid%5, gg = wgid/5: five consecutive blocks process
// the SAME 32 rows over adjacent 1024-col groups, so co-dispatched blocks
// cover each 20KB row contiguously (full DRAM page utilization) instead of
// 4KB-of-20KB strided. Index-only change; everything else identical to r15.
//
// Workspace (bytes):
//   wtpb     bf16 frag img 512x512 @ 0       (524,288)
//   Hb       u64  80x20480     @ 524,288     (13,107,200)
//   HTb      u64  320x5120     @ 13,631,488  (13,107,200)
//   inv_de   f32  5120         @ 26,738,688  (20,480)
//   inv_dv   f32  20480        @ 26,759,168  (81,920)
//   xpb      img  2560x256x16B @ 26,841,088  (10,485,760)
//   partialA bf16 16x256x5120  @ 37,326,848  (41,943,040)
//   t2p      img  640x256x16B  @ 79,269,888  (2,621,440)
//   partialB bf16 4x20480x256  @ 81,891,328  (41,943,040)  total ~124 MB

#define N_NODES 20000
#define M_EDGES 5000
#define MPAD    5120
#define NPAD    20480
#define NW      320
#define MW      80
#define DIN     256
#define DOUT    512
#define SPLITS  16
#define SPLITSB 4

typedef short bf16x8 __attribute__((ext_vector_type(8)));
typedef float f32x4 __attribute__((ext_vector_type(4)));
typedef unsigned long long u64;

#define MFMA16(A, B, C) __builtin_amdgcn_mfma_f32_16x16x32_bf16((A), (B), (C), 0, 0, 0)

__device__ __forceinline__ unsigned short f2b(float f) {
  unsigned u = __builtin_bit_cast(unsigned, f);
  return (unsigned short)((u + 0x7FFFu + ((u >> 16) & 1u)) >> 16);  // RNE
}

__device__ __forceinline__ float b2f(unsigned short b) {
  return __builtin_bit_cast(float, ((unsigned)b) << 16);
}

__device__ __forceinline__ void stage16(const void* g, void* l) {
  __builtin_amdgcn_global_load_lds(
      (const __attribute__((address_space(1))) unsigned int*)g,
      (__attribute__((address_space(3))) unsigned int*)l, 16, 0, 0);
}

// 8 bits -> 8 bf16 {0,1}
__device__ __forceinline__ bf16x8 expand8(unsigned b) {
  union { unsigned u[4]; bf16x8 v; } r;
  const unsigned t = b | (b << 15);
  r.u[0] = (t & 0x00010001u) * 0x3F80u;
  r.u[1] = ((t >> 2) & 0x00010001u) * 0x3F80u;
  r.u[2] = ((t >> 4) & 0x00010001u) * 0x3F80u;
  r.u[3] = ((t >> 6) & 0x00010001u) * 0x3F80u;
  return r.v;
}

// ---------------------------------------------------------------- prep: wtpb frag image
__global__ __launch_bounds__(256) void prep_kernel(const float* __restrict__ Wn,
                                                   const float* __restrict__ Wr,
                                                   unsigned short* __restrict__ wtpb) {
  const int q = blockIdx.x * 256 + threadIdx.x;  // < 262144
  const int j = q >> 9, k = q & 511;
  const float v = (k < 256) ? Wn[(size_t)k * 512 + j] : Wr[(size_t)(k - 256) * 512 + j];
  wtpb[(((size_t)(k >> 3) * 512 + j) << 3) + (k & 7)] = f2b(v);
}

// ---------------------------------------------------------------- xt
__global__ __launch_bounds__(256) void xt_kernel(const float* __restrict__ x,
                                                 unsigned short* __restrict__ xpb) {
  const int j = threadIdx.x;
  const int n8 = blockIdx.x;
  union { unsigned u[4]; bf16x8 v; } o;
#pragma unroll
  for (int p = 0; p < 4; ++p) {
    const int n = n8 * 8 + 2 * p;
    const float v0 = (n < N_NODES) ? x[(size_t)n * DIN + j] : 0.f;
    const float v1 = (n + 1 < N_NODES) ? x[(size_t)(n + 1) * DIN + j] : 0.f;
    o.u[p] = (unsigned)f2b(v0) | ((unsigned)f2b(v1) << 16);
  }
  *(bf16x8*)(xpb + ((size_t)n8 * 256 + j) * 8) = o.v;
}

// ---------------------------------------------------------------- pack v7: DRAM-page-coalesced block order
// grid 3200 1-D: h = wgid%5, gg = wgid/5 -> 5 consecutive blocks cover the
// same 32 rows contiguously across the full 20KB row. Thread owns 4 cols.
__global__ __launch_bounds__(256) void pack_kernel(const float* __restrict__ H,
                                                   unsigned* __restrict__ HTb32) {
  const int t = threadIdx.x;
  const int wgid = blockIdx.x;     // 0..3199
  const int h = wgid % 5;          // 1024-col group
  const int gg = wgid / 5;         // 32-row group
  const int g = gg >> 1, half = gg & 1;
  const int n0 = gg * 32;
  const int mc = h * 1024 + 4 * t; // this thread's 4 columns
  unsigned h0 = 0, h1 = 0, h2 = 0, h3 = 0;
  if (mc + 3 < M_EDGES) {
    const float* col = H + mc;
    if (n0 + 32 <= N_NODES) {
#pragma unroll
      for (int r = 0; r < 32; ++r) {
        const float4 v = *(const float4*)(col + (size_t)(n0 + r) * M_EDGES);
        h0 |= (unsigned)(v.x != 0.f) << r;
        h1 |= (unsigned)(v.y != 0.f) << r;
        h2 |= (unsigned)(v.z != 0.f) << r;
        h3 |= (unsigned)(v.w != 0.f) << r;
      }
    } else {
      for (int r = 0; r < 32; ++r) {
        const int n = n0 + r;
        if (n < N_NODES) {
          const float4 v = *(const float4*)(col + (size_t)n * M_EDGES);
          h0 |= (unsigned)(v.x != 0.f) << r;
          h1 |= (unsigned)(v.y != 0.f) << r;
          h2 |= (unsigned)(v.z != 0.f) << r;
          h3 |= (unsigned)(v.w != 0.f) << r;
        }
      }
    }
  } else if (mc < M_EDGES) {
    for (int r = 0; r < 32; ++r) {
      const int n = n0 + r;
      if (n < N_NODES) {
        const float* row = H + (size_t)n * M_EDGES;
        if (mc + 0 < M_EDGES) h0 |= (unsigned)(row[mc + 0] != 0.f) << r;
        if (mc + 1 < M_EDGES) h1 |= (unsigned)(row[mc + 1] != 0.f) << r;
        if (mc + 2 < M_EDGES) h2 |= (unsigned)(row[mc + 2] != 0.f) << r;
        if (mc + 3 < M_EDGES) h3 |= (unsigned)(row[mc + 3] != 0.f) << r;
      }
    }
  }
  unsigned* hp = HTb32 + ((size_t)g * MPAD + mc) * 2 + half;  // u64 half (LE)
  hp[0] = h0; hp[2] = h1; hp[4] = h2; hp[6] = h3;
}

// ---------------------------------------------------------------- bt: bit-transpose HTb -> Hb
__global__ __launch_bounds__(256) void bt_kernel(const u64* __restrict__ HTb,
                                                 u64* __restrict__ Hb) {
  const int t = threadIdx.x;
  const int w = t >> 6, l = t & 63;
  const int id = blockIdx.x * 4 + w;
  const int nw = id % NW;
  const int mw = id / NW;
  const u64 word = HTb[(size_t)nw * MPAD + mw * 64 + l];
  u64 out = 0;
  for (int r = 0; r < 64; ++r) {
    const u64 mask = __ballot(((word >> r) & 1ull) != 0);
    if (l == r) out = mask;
  }
  Hb[(size_t)mw * NPAD + nw * 64 + l] = out;
}

// ---------------------------------------------------------------- deg
__global__ __launch_bounds__(256) void deg_kernel(const u64* __restrict__ Hb,
                                                  const u64* __restrict__ HTb,
                                                  float* __restrict__ inv_de,
                                                  float* __restrict__ inv_dv) {
  const int g = blockIdx.x * 256 + threadIdx.x;
  if (g < MPAD) {
    int c = 0;
    for (int nw = 0; nw < NW; ++nw) c += __popcll(HTb[(size_t)nw * MPAD + g]);
    inv_de[g] = 1.f / fmaxf((float)c, 1.f);
  } else if (g < MPAD + NPAD) {
    const int n = g - MPAD;
    int c = 0;
#pragma unroll
    for (int mw = 0; mw < MW; ++mw) c += __popcll(Hb[(size_t)mw * NPAD + n]);
    inv_dv[n] = 1.f / fmaxf((float)c, 1.f);
  }
}

// ---------------------------------------------------------------- gemmA: partialA[s] = bf16(x^T @ H)  (r12-proven)
__global__ __launch_bounds__(256) void gemmA_kernel(const unsigned short* __restrict__ xpb,
                                                    const u64* __restrict__ HTb,
                                                    unsigned short* __restrict__ partial) {
  __shared__ char lds[2][16384];
  const int t = threadIdx.x;
  const int w = t >> 6, l = t & 63;
  const int lr = l & 15, lg = l >> 4;
  const int shl8 = lg * 8;
  const int wgid = blockIdx.x;
  const int mchunk = wgid >> 6;
  const int sj = wgid & 63;
  const int s = sj >> 2, jb = sj & 3;
  const int m0 = mchunk * 256 + w * 64;
  const int j0 = jb * 64;

  f32x4 acc[4][4] = {};
  const u64* bbase = HTb + (size_t)(s * 20) * MPAD + m0 + lr;
  const char* xb = (const char*)xpb;
  const int n8b = s * 160;
  const int sj0 = j0 + w * 16 + lr;

  u64 b00, b01, b02, b03, b04, b05, b06, b07;
  u64 b10, b11, b12, b13, b14, b15, b16, b17;

#define GA_LOADB(S, st_) do {                                                  \
    const u64* bp_ = bbase + (size_t)(st_) * 2 * MPAD;                         \
    b##S##0 = bp_[0]; b##S##1 = bp_[16]; b##S##2 = bp_[32]; b##S##3 = bp_[48]; \
    const u64* bq_ = bp_ + MPAD;                                               \
    b##S##4 = bq_[0]; b##S##5 = bq_[16]; b##S##6 = bq_[32]; b##S##7 = bq_[48]; \
  } while (0)

#define GA_STAGE(buf, st_) do {                                                \
    const size_t r0_ = (size_t)(n8b + (st_) * 16 + lg) * 256 + sj0;            \
    stage16(xb + (r0_) * 16,              &lds[buf][(w) * 1024 + l * 16]);     \
    stage16(xb + (r0_ + 4 * 256) * 16,    &lds[buf][(4 + w) * 1024 + l * 16]); \
    stage16(xb + (r0_ + 8 * 256) * 16,    &lds[buf][(8 + w) * 1024 + l * 16]); \
    stage16(xb + (r0_ + 12 * 256) * 16,   &lds[buf][(12 + w) * 1024 + l * 16]);\
  } while (0)

#define GA_JG(jg, BW) do {                                                     \
    const unsigned wlo_ = (unsigned)(BW), whi_ = (unsigned)((BW) >> 32);       \
    const bf16x8 e0_ = expand8((wlo_ >> shl8) & 255u);                         \
    const bf16x8 e1_ = expand8((whi_ >> shl8) & 255u);                         \
    acc[0][jg] = MFMA16(A00_, e0_, acc[0][jg]);                                \
    acc[1][jg] = MFMA16(A10_, e0_, acc[1][jg]);                                \
    acc[2][jg] = MFMA16(A20_, e0_, acc[2][jg]);                                \
    acc[3][jg] = MFMA16(A30_, e0_, acc[3][jg]);                                \
    acc[0][jg] = MFMA16(A01_, e1_, acc[0][jg]);                                \
    acc[1][jg] = MFMA16(A11_, e1_, acc[1][jg]);                                \
    acc[2][jg] = MFMA16(A21_, e1_, acc[2][jg]);                                \
    acc[3][jg] = MFMA16(A31_, e1_, acc[3][jg]);                                \
  } while (0)

#define GA_COMP(buf, h, W0, W1, W2, W3) do {                                   \
    const char* L_ = &lds[buf][(h) * 8192];                                    \
    const bf16x8 A00_ = *(const bf16x8*)(L_ + l * 16 + 0);                     \
    const bf16x8 A10_ = *(const bf16x8*)(L_ + l * 16 + 1024);                  \
    const bf16x8 A20_ = *(const bf16x8*)(L_ + l * 16 + 2048);                  \
    const bf16x8 A30_ = *(const bf16x8*)(L_ + l * 16 + 3072);                  \
    const bf16x8 A01_ = *(const bf16x8*)(L_ + l * 16 + 4096);                  \
    const bf16x8 A11_ = *(const bf16x8*)(L_ + l * 16 + 5120);                  \
    const bf16x8 A21_ = *(const bf16x8*)(L_ + l * 16 + 6144);                  \
    const bf16x8 A31_ = *(const bf16x8*)(L_ + l * 16 + 7168);                  \
    GA_JG(0, W0); GA_JG(1, W1); GA_JG(2, W2); GA_JG(3, W3);                    \
  } while (0)

  GA_LOADB(0, 0);
  GA_STAGE(0, 0);
  for (int st = 0; st < 10; st += 2) {
    const int n1 = (st + 1 < 10) ? st + 1 : 9;
    GA_LOADB(1, n1); GA_STAGE(1, n1);
    asm volatile("s_waitcnt vmcnt(12)" ::: "memory");
    __builtin_amdgcn_s_barrier();
    GA_COMP(0, 0, b00, b01, b02, b03);
    GA_COMP(0, 1, b04, b05, b06, b07);
    __builtin_amdgcn_s_barrier();
    const int n2 = (st + 2 < 10) ? st + 2 : 9;
    GA_LOADB(0, n2); GA_STAGE(0, n2);
    asm volatile("s_waitcnt vmcnt(12)" ::: "memory");
    __builtin_amdgcn_s_barrier();
    GA_COMP(1, 0, b10, b11, b12, b13);
    GA_COMP(1, 1, b14, b15, b16, b17);
    __builtin_amdgcn_s_barrier();
  }
#undef GA_LOADB
#undef GA_STAGE
#undef GA_JG
#undef GA_COMP

  unsigned short* pp = partial + (size_t)s * (DIN * MPAD);
#pragma unroll
  for (int fr = 0; fr < 4; ++fr)
#pragma unroll
    for (int r = 0; r < 4; ++r) {
      const int j = j0 + fr * 16 + lg * 4 + r;
#pragma unroll
      for (int jg = 0; jg < 4; ++jg)
        pp[(size_t)j * MPAD + m0 + jg * 16 + lr] = f2b(acc[fr][jg][r]);
    }
}

// ---------------------------------------------------------------- reduceA (bf16 partials)
__global__ __launch_bounds__(256) void reduceA_kernel(const unsigned short* __restrict__ partial,
                                                      const float* __restrict__ inv_de,
                                                      unsigned short* __restrict__ t2p) {
  const int t = threadIdx.x;
  const int m = blockIdx.x * 256 + t;
  const int jc = blockIdx.y * 16;
  const float e = inv_de[m];
  unsigned short* ob = t2p + ((size_t)(m >> 3) * 256) * 8 + (m & 7);
  for (int jj = 0; jj < 16; ++jj) {
    const int j = jc + jj;
    const unsigned short* p = partial + (size_t)j * MPAD + m;
    float s = 0.f;
#pragma unroll
    for (int sp = 0; sp < SPLITS; ++sp) s += b2f(p[(size_t)sp * (DIN * MPAD)]);
    ob[(size_t)j * 8] = f2b(s * e);
  }
}

// ---------------------------------------------------------------- gemmB: partialB[s] = bf16(H @ T2)  (r12-proven)
__global__ __launch_bounds__(256) void gemmB_kernel(const unsigned short* __restrict__ t2p,
                                                    const u64* __restrict__ Hb,
                                                    unsigned short* __restrict__ partialB) {
  __shared__ char lds[2][16384];
  const int t = threadIdx.x;
  const int w = t >> 6, l = t & 63;
  const int lr = l & 15, lg = l >> 4;
  const int shl8 = lg * 8;
  const int wgid = blockIdx.x;
  const int nchunk = wgid >> 4;
  const int sj = wgid & 15;
  const int s = sj >> 2, jb = sj & 3;
  const int n0 = nchunk * 256 + w * 64;
  const int j0 = jb * 64;

  f32x4 acc[4][4] = {};
  const u64* abase = Hb + (size_t)(s * 20) * NPAD + n0 + lr;
  const char* tb = (const char*)t2p;
  const int m8b = s * 160;
  const int sj0 = j0 + w * 16 + lr;

  u64 a00, a01, a02, a03, a04, a05, a06, a07;
  u64 a10, a11, a12, a13, a14, a15, a16, a17;

#define GB_LOADA(S, st_) do {                                                  \
    const u64* ap_ = abase + (size_t)(st_) * 2 * NPAD;                         \
    a##S##0 = ap_[0]; a##S##1 = ap_[16]; a##S##2 = ap_[32]; a##S##3 = ap_[48]; \
    const u64* aq_ = ap_ + NPAD;                                               \
    a##S##4 = aq_[0]; a##S##5 = aq_[16]; a##S##6 = aq_[32]; a##S##7 = aq_[48]; \
  } while (0)

#define GB_STAGE(buf, st_) do {                                                \
    const size_t r0_ = (size_t)(m8b + (st_) * 16 + lg) * 256 + sj0;            \
    stage16(tb + (r0_) * 16,              &lds[buf][(w) * 1024 + l * 16]);     \
    stage16(tb + (r0_ + 4 * 256) * 16,    &lds[buf][(4 + w) * 1024 + l * 16]); \
    stage16(tb + (r0_ + 8 * 256) * 16,    &lds[buf][(8 + w) * 1024 + l * 16]); \
    stage16(tb + (r0_ + 12 * 256) * 16,   &lds[buf][(12 + w) * 1024 + l * 16]);\
  } while (0)

#define GB_FR(fr, AW) do {                                                     \
    const unsigned wlo_ = (unsigned)(AW), whi_ = (unsigned)((AW) >> 32);       \
    const bf16x8 e0_ = expand8((wlo_ >> shl8) & 255u);                         \
    const bf16x8 e1_ = expand8((whi_ >> shl8) & 255u);                         \
    acc[fr][0] = MFMA16(e0_, B00_, acc[fr][0]);                                \
    acc[fr][1] = MFMA16(e0_, B10_, acc[fr][1]);                                \
    acc[fr][2] = MFMA16(e0_, B20_, acc[fr][2]);                                \
    acc[fr][3] = MFMA16(e0_, B30_, acc[fr][3]);                                \
    acc[fr][0] = MFMA16(e1_, B01_, acc[fr][0]);                                \
    acc[fr][1] = MFMA16(e1_, B11_, acc[fr][1]);                                \
    acc[fr][2] = MFMA16(e1_, B21_, acc[fr][2]);                                \
    acc[fr][3] = MFMA16(e1_, B31_, acc[fr][3]);                                \
  } while (0)

#define GB_COMP(buf, h, W0, W1, W2, W3) do {                                   \
    const char* L_ = &lds[buf][(h) * 8192];                                    \
    const bf16x8 B00_ = *(const bf16x8*)(L_ + l * 16 + 0);                     \
    const bf16x8 B10_ = *(const bf16x8*)(L_ + l * 16 + 1024);                  \
    const bf16x8 B20_ = *(const bf16x8*)(L_ + l * 16 + 2048);                  \
    const bf16x8 B30_ = *(const bf16x8*)(L_ + l * 16 + 3072);                  \
    const bf16x8 B01_ = *(const bf16x8*)(L_ + l * 16 + 4096);                  \
    const bf16x8 B11_ = *(const bf16x8*)(L_ + l * 16 + 5120);                  \
    const bf16x8 B21_ = *(const bf16x8*)(L_ + l * 16 + 6144);                  \
    const bf16x8 B31_ = *(const bf16x8*)(L_ + l * 16 + 7168);                  \
    GB_FR(0, W0); GB_FR(1, W1); GB_FR(2, W2); GB_FR(3, W3);                    \
  } while (0)

  GB_LOADA(0, 0);
  GB_STAGE(0, 0);
  for (int st = 0; st < 10; st += 2) {
    const int n1 = (st + 1 < 10) ? st + 1 : 9;
    GB_LOADA(1, n1); GB_STAGE(1, n1);
    asm volatile("s_waitcnt vmcnt(12)" ::: "memory");
    __builtin_amdgcn_s_barrier();
    GB_COMP(0, 0, a00, a01, a02, a03);
    GB_COMP(0, 1, a04, a05, a06, a07);
    __builtin_amdgcn_s_barrier();
    const int n2 = (st + 2 < 10) ? st + 2 : 9;
    GB_LOADA(0, n2); GB_STAGE(0, n2);
    asm volatile("s_waitcnt vmcnt(12)" ::: "memory");
    __builtin_amdgcn_s_barrier();
    GB_COMP(1, 0, a10, a11, a12, a13);
    GB_COMP(1, 1, a14, a15, a16, a17);
    __builtin_amdgcn_s_barrier();
  }
#undef GB_LOADA
#undef GB_STAGE
#undef GB_FR
#undef GB_COMP

  unsigned short* pp = partialB + (size_t)s * ((size_t)NPAD * DIN);
#pragma unroll
  for (int fr = 0; fr < 4; ++fr) {
#pragma unroll
    for (int r = 0; r < 4; ++r) {
      const int n = n0 + fr * 16 + lg * 4 + r;
#pragma unroll
      for (int jg = 0; jg < 4; ++jg)
        pp[(size_t)n * DIN + j0 + jg * 16 + lr] = f2b(acc[fr][jg][r]);
    }
  }
}

// ---------------------------------------------------------------- gemmC2 v2 (r12-proven): fused reduceB + [T3|x]@WT + LN
__global__ __launch_bounds__(512) void gemmC2_kernel(const unsigned short* __restrict__ partialB,
                                                     const float* __restrict__ inv_dv,
                                                     const float* __restrict__ x,
                                                     const unsigned short* __restrict__ wtpb,
                                                     const float* __restrict__ gamma,
                                                     const float* __restrict__ beta,
                                                     float* __restrict__ out) {
  __shared__ char ldsA[65536];        // A tile: 64 rows x 512 k bf16 (1024B rows, xor-swz)
  __shared__ float lnred[2][64][8];
  const int t = threadIdx.x;
  const int w = t >> 6, l = t & 63;
  const int lr = l & 15, lg = l >> 4;
  const int n0 = blockIdx.x * 64;

  // Phase 1: T3 tile = bf16((sum_sp partialB) * inv_dv) -> ldsA k<256
  {
    const int k8 = t & 31;
    const int rb = t >> 5;
#pragma unroll
    for (int pass = 0; pass < 4; ++pass) {
      const int r = pass * 16 + rb;
      const size_t base = (size_t)(n0 + r) * 256 + k8 * 8;
      float sum[8] = {0.f, 0.f, 0.f, 0.f, 0.f, 0.f, 0.f, 0.f};
#pragma unroll
      for (int sp = 0; sp < SPLITSB; ++sp) {
        const bf16x8 v = *(const bf16x8*)(partialB + (size_t)sp * ((size_t)NPAD * DIN) + base);
#pragma unroll
        for (int i = 0; i < 8; ++i) sum[i] += b2f((unsigned short)v[i]);
      }
      const float dv = inv_dv[n0 + r];
      union { unsigned u[4]; bf16x8 v; } o;
#pragma unroll
      for (int p = 0; p < 4; ++p)
        o.u[p] = (unsigned)f2b(sum[2 * p] * dv) | ((unsigned)f2b(sum[2 * p + 1] * dv) << 16);
      *(bf16x8*)(ldsA + r * 1024 + ((k8 * 16) ^ ((r & 7) << 4))) = o.v;
    }
  }
  // Phase 2: x tile -> ldsA k in [256,512)
  {
    const int c4 = t & 63;
    const int rb = t >> 6;
#pragma unroll
    for (int pass = 0; pass < 8; ++pass) {
      const int r = pass * 8 + rb;
      float4 v = make_float4(0.f, 0.f, 0.f, 0.f);
      if (n0 + r < N_NODES) v = *(const float4*)(x + (size_t)(n0 + r) * DIN + c4 * 4);
      const unsigned u0 = (unsigned)f2b(v.x) | ((unsigned)f2b(v.y) << 16);
      const unsigned u1 = (unsigned)f2b(v.z) | ((unsigned)f2b(v.w) << 16);
      const int byte0 = 512 + c4 * 8;
      const int off = ((byte0 & ~15) ^ ((r & 7) << 4)) + (byte0 & 8);
      *(uint2*)(ldsA + r * 1024 + off) = make_uint2(u0, u1);
    }
  }
  __syncthreads();

  f32x4 acc[4][4] = {};
  const int wcol = w * 64;
#pragma unroll 2
  for (int kt = 0; kt < 16; ++kt) {
    bf16x8 bf[4];
#pragma unroll
    for (int jg = 0; jg < 4; ++jg) {
      const int col = wcol + jg * 16 + lr;
      bf[jg] = *(const bf16x8*)(wtpb + (((size_t)(kt * 4 + lg) * 512 + col) << 3));
    }
    const int kbA = kt * 64 + lg * 16;
#pragma unroll
    for (int fr = 0; fr < 4; ++fr) {
      const int row = fr * 16 + lr;
      const bf16x8 af = *(const bf16x8*)(ldsA + row * 1024 + (kbA ^ ((row & 7) << 4)));
#pragma unroll
      for (int jg = 0; jg < 4; ++jg)
        acc[fr][jg] = MFMA16(af, bf[jg], acc[fr][jg]);
    }
  }

#pragma unroll
  for (int fr = 0; fr < 4; ++fr)
#pragma unroll
    for (int r = 0; r < 4; ++r) {
      float s = 0.f, s2 = 0.f;
#pragma unroll
      for (int jg = 0; jg < 4; ++jg) {
        const float v = acc[fr][jg][r];
        s += v; s2 += v * v;
      }
#pragma unroll
      for (int m = 1; m < 16; m <<= 1) {
        s += __shfl_xor(s, m, 64);
        s2 += __shfl_xor(s2, m, 64);
      }
      if (lr == 0) {
        const int row = fr * 16 + lg * 4 + r;
        lnred[0][row][w] = s;
        lnred[1][row][w] = s2;
      }
    }
  __syncthreads();

#pragma unroll
  for (int fr = 0; fr < 4; ++fr) {
#pragma unroll
    for (int r = 0; r < 4; ++r) {
      const int row = fr * 16 + lg * 4 + r;
      float S = 0.f, S2 = 0.f;
#pragma unroll
      for (int ww = 0; ww < 8; ++ww) { S += lnred[0][row][ww]; S2 += lnred[1][row][ww]; }
      const float mu = S * (1.f / 512.f);
      const float rs = rsqrtf(S2 * (1.f / 512.f) - mu * mu + 1e-5f);
      const int gn = n0 + row;
      if (gn < N_NODES) {
#pragma unroll
        for (int jg = 0; jg < 4; ++jg) {
          const int col = wcol + jg * 16 + lr;
          out[(size_t)gn * DOUT + col] = (acc[fr][jg][r] - mu) * rs * gamma[col] + beta[col];
        }
      }
    }
  }
}

// ----------------------------------------------------------------
extern "C" void kernel_launch(void* const* d_in, const int* in_sizes, int n_in,
                              void* d_out, int out_size, void* d_ws, size_t ws_size,
                              hipStream_t stream) {
  (void)in_sizes; (void)n_in; (void)out_size; (void)ws_size;
  const float* x = (const float*)d_in[0];
  const float* H = (const float*)d_in[1];
  const float* Wn = (const float*)d_in[2];
  const float* Wr = (const float*)d_in[3];
  const float* gamma = (const float*)d_in[4];
  const float* beta = (const float*)d_in[5];
  float* out = (float*)d_out;
  char* ws = (char*)d_ws;

  unsigned short* wtpb     = (unsigned short*)(ws + 0);
  u64* Hb                  = (u64*)(ws + 524288);
  u64* HTb                 = (u64*)(ws + 13631488);
  float* inv_de            = (float*)(ws + 26738688);
  float* inv_dv            = (float*)(ws + 26759168);
  unsigned short* xpb      = (unsigned short*)(ws + 26841088);
  unsigned short* partialA = (unsigned short*)(ws + 37326848);
  unsigned short* t2p      = (unsigned short*)(ws + 79269888);
  unsigned short* partialB = (unsigned short*)(ws + 81891328);

  prep_kernel<<<dim3(1024), dim3(256), 0, stream>>>(Wn, Wr, wtpb);
  xt_kernel<<<dim3(2560), dim3(256), 0, stream>>>(x, xpb);
  pack_kernel<<<dim3(3200), dim3(256), 0, stream>>>(H, (unsigned*)HTb);
  bt_kernel<<<dim3(6400), dim3(256), 0, stream>>>(HTb, Hb);
  deg_kernel<<<dim3(100), dim3(256), 0, stream>>>(Hb, HTb, inv_de, inv_dv);
  gemmA_kernel<<<dim3(1280), dim3(256), 0, stream>>>(xpb, HTb, partialA);
  reduceA_kernel<<<dim3(20, 16), dim3(256), 0, stream>>>(partialA, inv_de, t2p);
  gemmB_kernel<<<dim3(1280), dim3(256), 0, stream>>>(t2p, Hb, partialB);
  gemmC2_kernel<<<dim3(313), dim3(512), 0, stream>>>(partialB, inv_dv, x, wtpb,
                                                     gamma, beta, out);
}